// Round 1
// baseline (209.215 us; speedup 1.0000x reference)
//
#include <hip/hip_runtime.h>

typedef __bf16 bf16x8 __attribute__((ext_vector_type(8)));
typedef float f32x4 __attribute__((ext_vector_type(4)));
typedef unsigned short u16;
typedef unsigned short u16x4 __attribute__((ext_vector_type(4)));
typedef unsigned short u16x8 __attribute__((ext_vector_type(8)));

#define AS1 __attribute__((address_space(1)))
#define AS3 __attribute__((address_space(3)))

__device__ __forceinline__ u16 f2bf(float f) {
  unsigned u = __builtin_bit_cast(unsigned, f);
  u += 0x7fffu + ((u >> 16) & 1u);
  return (u16)(u >> 16);
}
__device__ __forceinline__ float bf2f(u16 h) {
  unsigned u = ((unsigned)h) << 16;
  return __builtin_bit_cast(float, u);
}

// ---------------- fp32 -> bf16 convert ----------------
__global__ __launch_bounds__(256) void cvt_f32_bf16(const float* __restrict__ in,
                                                    u16* __restrict__ out, int n) {
  int i = (blockIdx.x * 256 + threadIdx.x) * 4;
  if (i >= n) return;
  float4 v = *reinterpret_cast<const float4*>(in + i);
  u16x4 o;
  o.x = f2bf(v.x); o.y = f2bf(v.y); o.z = f2bf(v.z); o.w = f2bf(v.w);
  *reinterpret_cast<u16x4*>(out + i) = o;
}

// ---------------- GEMM: C[M][N] = A[M][K] * W[N][K]^T (bf16 in, fp32 acc) ----------------
// 128x128 tile, BK=32, 256 threads (4 waves, 2x2), global_load_lds staging (m97 structure)
template <int OUTF32>
__global__ __launch_bounds__(256, 2) void gemm_bt(const u16* __restrict__ A,
                                                  const u16* __restrict__ W,
                                                  void* __restrict__ C, int N, int K) {
  __shared__ __align__(16) u16 As[128 * 32];
  __shared__ __align__(16) u16 Bs[128 * 32];
  const int tid = threadIdx.x;
  const int lane = tid & 63;
  const int wid = tid >> 6;
  const int wm = wid >> 1, wn = wid & 1;
  const int l16 = lane & 15, g4 = lane >> 4;
  const long bm = blockIdx.x, bn = blockIdx.y;

  const int srow = tid >> 2;         // 0..63 (chunk row)
  const int scol = (tid & 3) * 8;    // elem col offset in row
  const u16* aA0 = A + (bm * 128 + srow) * (long)K + scol;
  const u16* aA1 = aA0 + 64 * (long)K;
  const u16* aW0 = W + (bn * 128 + srow) * (long)K + scol;
  const u16* aW1 = aW0 + 64 * (long)K;

  f32x4 acc[4][4] = {};

  for (int kt = 0; kt < K; kt += 32) {
    __builtin_amdgcn_global_load_lds((AS1 void*)(aA0 + kt), (AS3 void*)(&As[tid * 8]), 16, 0, 0);
    __builtin_amdgcn_global_load_lds((AS1 void*)(aA1 + kt), (AS3 void*)(&As[2048 + tid * 8]), 16, 0, 0);
    __builtin_amdgcn_global_load_lds((AS1 void*)(aW0 + kt), (AS3 void*)(&Bs[tid * 8]), 16, 0, 0);
    __builtin_amdgcn_global_load_lds((AS1 void*)(aW1 + kt), (AS3 void*)(&Bs[2048 + tid * 8]), 16, 0, 0);
    __syncthreads();
    bf16x8 af[4], bfr[4];
#pragma unroll
    for (int m = 0; m < 4; ++m)
      af[m] = *reinterpret_cast<const bf16x8*>(&As[(wm * 64 + m * 16 + l16) * 32 + g4 * 8]);
#pragma unroll
    for (int n = 0; n < 4; ++n)
      bfr[n] = *reinterpret_cast<const bf16x8*>(&Bs[(wn * 64 + n * 16 + l16) * 32 + g4 * 8]);
#pragma unroll
    for (int m = 0; m < 4; ++m)
#pragma unroll
      for (int n = 0; n < 4; ++n)
        acc[m][n] = __builtin_amdgcn_mfma_f32_16x16x32_bf16(af[m], bfr[n], acc[m][n], 0, 0, 0);
    __syncthreads();
  }

#pragma unroll
  for (int m = 0; m < 4; ++m) {
#pragma unroll
    for (int n = 0; n < 4; ++n) {
#pragma unroll
      for (int j = 0; j < 4; ++j) {
        long row = bm * 128 + wm * 64 + m * 16 + g4 * 4 + j;
        long col = bn * 128 + wn * 64 + n * 16 + l16;
        if (OUTF32)
          reinterpret_cast<float*>(C)[row * N + col] = acc[m][n][j];
        else
          reinterpret_cast<u16*>(C)[row * N + col] = f2bf(acc[m][n][j]);
      }
    }
  }
}

// ---------------- RMSNorm on q,k head-groups of qkv (in place, bf16) ----------------
// row = (b*L + l)*NH + h for q (isK=0) then k (isK=1); 64 elems per row.
__global__ __launch_bounds__(256) void rmsnorm_qk(u16* __restrict__ qkv,
                                                  const float* __restrict__ qw,
                                                  const float* __restrict__ kw) {
  const int tid = threadIdx.x;
  const int l16 = tid & 15;
  const long row = (long)blockIdx.x * 16 + (tid >> 4);  // 0..131071
  const int isK = row >= 65536;
  const long r = isK ? row - 65536 : row;
  const long bl = r >> 4;
  const int h = (int)(r & 15);
  u16* p = qkv + bl * 3072 + (isK ? 1024 : 0) + h * 64 + l16 * 4;
  u16x4 v = *reinterpret_cast<const u16x4*>(p);
  float f0 = bf2f(v.x), f1 = bf2f(v.y), f2 = bf2f(v.z), f3 = bf2f(v.w);
  float ss = f0 * f0 + f1 * f1 + f2 * f2 + f3 * f3;
  ss += __shfl_xor(ss, 1);
  ss += __shfl_xor(ss, 2);
  ss += __shfl_xor(ss, 4);
  ss += __shfl_xor(ss, 8);
  const float inv = rsqrtf(ss * (1.0f / 64.0f) + 1e-5f);
  const float* w = isK ? kw : qw;
  u16x4 o;
  o.x = f2bf(f0 * inv * w[l16 * 4 + 0]);
  o.y = f2bf(f1 * inv * w[l16 * 4 + 1]);
  o.z = f2bf(f2 * inv * w[l16 * 4 + 2]);
  o.w = f2bf(f3 * inv * w[l16 * 4 + 3]);
  *reinterpret_cast<u16x4*>(p) = o;
}

// ---------------- causal flash attention ----------------
// grid: x = q-tile (32), y = b*NH (32). 256 threads = 4 waves, 16 q-rows/wave.
// qkv layout: [b*L + l][3072]; q at +0, k at +1024, v at +2048, head h at h*64.
__global__ __launch_bounds__(256, 2) void attn_causal(const u16* __restrict__ qkv,
                                                      u16* __restrict__ o) {
  constexpr int PAD = 72;  // bf16 elems per LDS row (64 + 8 pad -> 144B rows)
  __shared__ __align__(16) u16 Klds[64 * PAD];
  __shared__ __align__(16) u16 Vt[64 * PAD];        // V transposed: [d][key]
  __shared__ __align__(16) u16 Plds[4][16 * PAD];   // per-wave P tile
  const int tid = threadIdx.x, lane = tid & 63, wid = tid >> 6;
  const int l16 = lane & 15, g4 = lane >> 4;
  const int qt = blockIdx.x;
  const int bh = blockIdx.y;
  const long base_bl = (long)(bh >> 4) * 2048;
  const long hoff = (bh & 15) * 64;

  // Q fragments in registers (A-operand rows = l16)
  const long qrow = (long)qt * 64 + wid * 16 + l16;
  const u16* qp = qkv + (base_bl + qrow) * 3072 + hoff;
  const bf16x8 qf0 = *reinterpret_cast<const bf16x8*>(qp + g4 * 8);
  const bf16x8 qf1 = *reinterpret_cast<const bf16x8*>(qp + 32 + g4 * 8);

  f32x4 accv[4] = {};
  float m_r[4] = {-3e38f, -3e38f, -3e38f, -3e38f};
  float l_r[4] = {0.f, 0.f, 0.f, 0.f};
  const float cl = 0.125f * 1.4426950408889634f;  // scale * log2(e)

  const u16* kbase = qkv + base_bl * 3072 + 1024 + hoff;
  const u16* vbase = qkv + base_bl * 3072 + 2048 + hoff;

  for (int kt = 0; kt <= qt; ++kt) {
    // ---- stage K (coalesced rows), padded LDS
    {
      const int key0 = tid >> 3;          // 0..31
      const int fb = (tid & 7) * 8;       // elem offset
      const u16* g0 = kbase + (kt * 64 + key0) * 3072L + fb;
      u16x8 kv0 = *reinterpret_cast<const u16x8*>(g0);
      u16x8 kv1 = *reinterpret_cast<const u16x8*>(g0 + 32 * 3072L);
      *reinterpret_cast<u16x8*>(&Klds[key0 * PAD + fb]) = kv0;
      *reinterpret_cast<u16x8*>(&Klds[(key0 + 32) * PAD + fb]) = kv1;
    }
    // ---- stage V transposed: thread -> key = lane, d-blocks wid and wid+4
    {
      const u16* gv = vbase + (kt * 64 + lane) * 3072L;
      u16x8 v0 = *reinterpret_cast<const u16x8*>(gv + wid * 8);
      u16x8 v1 = *reinterpret_cast<const u16x8*>(gv + (wid + 4) * 8);
#pragma unroll
      for (int j = 0; j < 8; ++j) Vt[(wid * 8 + j) * PAD + lane] = v0[j];
#pragma unroll
      for (int j = 0; j < 8; ++j) Vt[((wid + 4) * 8 + j) * PAD + lane] = v1[j];
    }
    __syncthreads();

    // ---- S = Q K^T : 4 key-fragments of 16
    f32x4 s[4];
#pragma unroll
    for (int kn = 0; kn < 4; ++kn) {
      bf16x8 k0 = *reinterpret_cast<const bf16x8*>(&Klds[(kn * 16 + l16) * PAD + g4 * 8]);
      bf16x8 k1 = *reinterpret_cast<const bf16x8*>(&Klds[(kn * 16 + l16) * PAD + 32 + g4 * 8]);
      f32x4 z = {};
      z = __builtin_amdgcn_mfma_f32_16x16x32_bf16(qf0, k0, z, 0, 0, 0);
      z = __builtin_amdgcn_mfma_f32_16x16x32_bf16(qf1, k1, z, 0, 0, 0);
      s[kn] = z;
    }
    if (kt == qt) {  // diagonal tile: mask key > q
#pragma unroll
      for (int kn = 0; kn < 4; ++kn) {
        const int keyl = kn * 16 + l16;
#pragma unroll
        for (int j = 0; j < 4; ++j) {
          const int ql = wid * 16 + g4 * 4 + j;
          if (keyl > ql) s[kn][j] = -3e38f;
        }
      }
    }

    // ---- online softmax (rows live on lanes: row = g4*4+j, cols across l16)
    float corr[4];
#pragma unroll
    for (int j = 0; j < 4; ++j) {
      float m0 = fmaxf(fmaxf(s[0][j], s[1][j]), fmaxf(s[2][j], s[3][j]));
      m0 = fmaxf(m0, __shfl_xor(m0, 1));
      m0 = fmaxf(m0, __shfl_xor(m0, 2));
      m0 = fmaxf(m0, __shfl_xor(m0, 4));
      m0 = fmaxf(m0, __shfl_xor(m0, 8));
      const float mnew = fmaxf(m_r[j], m0);
      corr[j] = exp2f((m_r[j] - mnew) * cl);
      m_r[j] = mnew;
      float sum = 0.f;
#pragma unroll
      for (int kn = 0; kn < 4; ++kn) {
        const float e = exp2f((s[kn][j] - mnew) * cl);
        s[kn][j] = e;
        sum += e;
      }
      sum += __shfl_xor(sum, 1);
      sum += __shfl_xor(sum, 2);
      sum += __shfl_xor(sum, 4);
      sum += __shfl_xor(sum, 8);
      l_r[j] = l_r[j] * corr[j] + sum;
    }
#pragma unroll
    for (int n = 0; n < 4; ++n)
#pragma unroll
      for (int j = 0; j < 4; ++j) accv[n][j] *= corr[j];

    // ---- P -> LDS (row = q = g4*4+j, col = key)
#pragma unroll
    for (int kn = 0; kn < 4; ++kn)
#pragma unroll
      for (int j = 0; j < 4; ++j)
        Plds[wid][(g4 * 4 + j) * PAD + kn * 16 + l16] = f2bf(s[kn][j]);

    // ---- O += P V  (A = P rows l16, B = V^T rows = d)
#pragma unroll
    for (int ks = 0; ks < 2; ++ks) {
      bf16x8 a = *reinterpret_cast<const bf16x8*>(&Plds[wid][l16 * PAD + ks * 32 + g4 * 8]);
#pragma unroll
      for (int n = 0; n < 4; ++n) {
        bf16x8 bb = *reinterpret_cast<const bf16x8*>(&Vt[(n * 16 + l16) * PAD + ks * 32 + g4 * 8]);
        accv[n] = __builtin_amdgcn_mfma_f32_16x16x32_bf16(a, bb, accv[n], 0, 0, 0);
      }
    }
    __syncthreads();
  }

  // ---- epilogue: o[b, l, h*64 + d] bf16
  const long orow = (long)qt * 64 + wid * 16 + g4 * 4;
  u16* op = o + (base_bl + orow) * 1024 + hoff;
#pragma unroll
  for (int n = 0; n < 4; ++n) {
#pragma unroll
    for (int j = 0; j < 4; ++j) {
      op[j * 1024 + n * 16 + l16] = f2bf(accv[n][j] / l_r[j]);
    }
  }
}

extern "C" void kernel_launch(void* const* d_in, const int* in_sizes, int n_in,
                              void* d_out, int out_size, void* d_ws, size_t ws_size,
                              hipStream_t stream) {
  const float* x = (const float*)d_in[0];
  // d_in[1] = mask (causal tril -- not needed)
  const float* w_qkv = (const float*)d_in[2];
  const float* w_fc = (const float*)d_in[3];
  const float* qw = (const float*)d_in[4];
  const float* kw = (const float*)d_in[5];
  // d_in[6] = subset_attention_size: with a causal mask the split is an identity.
  float* out = (float*)d_out;

  char* ws = (char*)d_ws;
  u16* xb    = (u16*)(ws);                   // 8 MB  (4194304)
  u16* wqkvb = (u16*)(ws + (8L << 20));      // 6 MB  (3145728)
  u16* wfcb  = (u16*)(ws + (14L << 20));     // 2 MB  (1048576)
  u16* qkv   = (u16*)(ws + (16L << 20));     // 24 MB (12582912)
  u16* ob    = (u16*)(ws + (40L << 20));     // 8 MB  (4194304)

  cvt_f32_bf16<<<4096, 256, 0, stream>>>(x, xb, 4194304);
  cvt_f32_bf16<<<3072, 256, 0, stream>>>(w_qkv, wqkvb, 3145728);
  cvt_f32_bf16<<<1024, 256, 0, stream>>>(w_fc, wfcb, 1048576);

  gemm_bt<0><<<dim3(32, 24), 256, 0, stream>>>(xb, wqkvb, (void*)qkv, 3072, 1024);
  rmsnorm_qk<<<8192, 256, 0, stream>>>(qkv, qw, kw);
  attn_causal<<<dim3(32, 32), 256, 0, stream>>>(qkv, ob);
  gemm_bt<1><<<dim3(32, 8), 256, 0, stream>>>(ob, wfcb, (void*)out, 1024, 1024);
}

// Round 2
// 134.580 us; speedup vs baseline: 1.5546x; 1.5546x over previous
//
#include <hip/hip_runtime.h>

typedef __bf16 bf16x8 __attribute__((ext_vector_type(8)));
typedef float f32x4 __attribute__((ext_vector_type(4)));
typedef unsigned short u16;
typedef unsigned int u32;
typedef unsigned short u16x4 __attribute__((ext_vector_type(4)));
typedef unsigned short u16x8 __attribute__((ext_vector_type(8)));

#define AS1 __attribute__((address_space(1)))
#define AS3 __attribute__((address_space(3)))

__device__ __forceinline__ u16 f2bf(float f) {
  unsigned u = __builtin_bit_cast(unsigned, f);
  u += 0x7fffu + ((u >> 16) & 1u);
  return (u16)(u >> 16);
}
__device__ __forceinline__ float bf2f(u16 h) {
  unsigned u = ((unsigned)h) << 16;
  return __builtin_bit_cast(float, u);
}

// ---------------- fp32 -> bf16 convert ----------------
__global__ __launch_bounds__(256) void cvt_f32_bf16(const float* __restrict__ in,
                                                    u16* __restrict__ out, int n) {
  int i = (blockIdx.x * 256 + threadIdx.x) * 4;
  if (i >= n) return;
  float4 v = *reinterpret_cast<const float4*>(in + i);
  u16x4 o;
  o.x = f2bf(v.x); o.y = f2bf(v.y); o.z = f2bf(v.z); o.w = f2bf(v.w);
  *reinterpret_cast<u16x4*>(out + i) = o;
}

// ---------------- GEMM: C[M][N] = A[M][K] * W[N][K]^T (bf16 in, fp32 acc) ----------------
template <int OUTF32>
__global__ __launch_bounds__(256, 2) void gemm_bt(const u16* __restrict__ A,
                                                  const u16* __restrict__ W,
                                                  void* __restrict__ C, int N, int K) {
  __shared__ __align__(16) u16 As[128 * 32];
  __shared__ __align__(16) u16 Bs[128 * 32];
  const int tid = threadIdx.x;
  const int lane = tid & 63;
  const int wid = tid >> 6;
  const int wm = wid >> 1, wn = wid & 1;
  const int l16 = lane & 15, g4 = lane >> 4;
  const long bm = blockIdx.x, bn = blockIdx.y;

  const int srow = tid >> 2;
  const int scol = (tid & 3) * 8;
  const u16* aA0 = A + (bm * 128 + srow) * (long)K + scol;
  const u16* aA1 = aA0 + 64 * (long)K;
  const u16* aW0 = W + (bn * 128 + srow) * (long)K + scol;
  const u16* aW1 = aW0 + 64 * (long)K;

  f32x4 acc[4][4] = {};

  for (int kt = 0; kt < K; kt += 32) {
    __builtin_amdgcn_global_load_lds((AS1 void*)(aA0 + kt), (AS3 void*)(&As[tid * 8]), 16, 0, 0);
    __builtin_amdgcn_global_load_lds((AS1 void*)(aA1 + kt), (AS3 void*)(&As[2048 + tid * 8]), 16, 0, 0);
    __builtin_amdgcn_global_load_lds((AS1 void*)(aW0 + kt), (AS3 void*)(&Bs[tid * 8]), 16, 0, 0);
    __builtin_amdgcn_global_load_lds((AS1 void*)(aW1 + kt), (AS3 void*)(&Bs[2048 + tid * 8]), 16, 0, 0);
    __syncthreads();
    bf16x8 af[4], bfr[4];
#pragma unroll
    for (int m = 0; m < 4; ++m)
      af[m] = *reinterpret_cast<const bf16x8*>(&As[(wm * 64 + m * 16 + l16) * 32 + g4 * 8]);
#pragma unroll
    for (int n = 0; n < 4; ++n)
      bfr[n] = *reinterpret_cast<const bf16x8*>(&Bs[(wn * 64 + n * 16 + l16) * 32 + g4 * 8]);
#pragma unroll
    for (int m = 0; m < 4; ++m)
#pragma unroll
      for (int n = 0; n < 4; ++n)
        acc[m][n] = __builtin_amdgcn_mfma_f32_16x16x32_bf16(af[m], bfr[n], acc[m][n], 0, 0, 0);
    __syncthreads();
  }

#pragma unroll
  for (int m = 0; m < 4; ++m) {
#pragma unroll
    for (int n = 0; n < 4; ++n) {
#pragma unroll
      for (int j = 0; j < 4; ++j) {
        long row = bm * 128 + wm * 64 + m * 16 + g4 * 4 + j;
        long col = bn * 128 + wn * 64 + n * 16 + l16;
        if (OUTF32)
          reinterpret_cast<float*>(C)[row * N + col] = acc[m][n][j];
        else
          reinterpret_cast<u16*>(C)[row * N + col] = f2bf(acc[m][n][j]);
      }
    }
  }
}

// ---------------- RMSNorm on q,k head-groups of qkv (in place, bf16) ----------------
__global__ __launch_bounds__(256) void rmsnorm_qk(u16* __restrict__ qkv,
                                                  const float* __restrict__ qw,
                                                  const float* __restrict__ kw) {
  const int tid = threadIdx.x;
  const int l16 = tid & 15;
  const long row = (long)blockIdx.x * 16 + (tid >> 4);
  const int isK = row >= 65536;
  const long r = isK ? row - 65536 : row;
  const long bl = r >> 4;
  const int h = (int)(r & 15);
  u16* p = qkv + bl * 3072 + (isK ? 1024 : 0) + h * 64 + l16 * 4;
  u16x4 v = *reinterpret_cast<const u16x4*>(p);
  float f0 = bf2f(v.x), f1 = bf2f(v.y), f2 = bf2f(v.z), f3 = bf2f(v.w);
  float ss = f0 * f0 + f1 * f1 + f2 * f2 + f3 * f3;
  ss += __shfl_xor(ss, 1);
  ss += __shfl_xor(ss, 2);
  ss += __shfl_xor(ss, 4);
  ss += __shfl_xor(ss, 8);
  const float inv = rsqrtf(ss * (1.0f / 64.0f) + 1e-5f);
  const float* w = isK ? kw : qw;
  u16x4 o;
  o.x = f2bf(f0 * inv * w[l16 * 4 + 0]);
  o.y = f2bf(f1 * inv * w[l16 * 4 + 1]);
  o.z = f2bf(f2 * inv * w[l16 * 4 + 2]);
  o.w = f2bf(f3 * inv * w[l16 * 4 + 3]);
  *reinterpret_cast<u16x4*>(p) = o;
}

// ---------------- causal flash attention, paired q-tiles, swapped QK^T ----------------
// grid: x = q-pair (16), y = b*NH (32). 256 threads = 4 waves.
// Block handles q-tiles qlo=x and qhi=31-x (equal total work: 33 tile-computations).
// S^T = mfma(K, Q): lane l16 owns one q-row; keys live on (g4, reg j).
__global__ __launch_bounds__(256, 2) void attn_causal(const u16* __restrict__ qkv,
                                                      u16* __restrict__ o) {
  __shared__ __align__(16) u16 Klds[2][4096];        // 64 rows x 64 d, source-swizzled
  __shared__ __align__(16) u16 Vt[2][64 * 72];       // V^T: [d][key], pad 72
  __shared__ __align__(16) u16 Plds[4][2][16 * 72];  // per-wave P, [q(16)][key(64)], pad 72

  const int tid = threadIdx.x, lane = tid & 63, wid = tid >> 6;
  const int l16 = lane & 15, g4 = lane >> 4;
  const int qlo = blockIdx.x, qhi = 31 - qlo;
  const int bh = blockIdx.y;
  const long base = (long)(bh >> 4) * 2048 * 3072 + (bh & 15) * 64;
  const u16* qb = qkv + base;
  const u16* kb = qkv + base + 1024;
  const u16* vb = qkv + base + 2048;

  // Q fragments (B-operand: lane l16 = q-row, elems = d)
  const u16* qpA = qb + ((long)qlo * 64 + wid * 16 + l16) * 3072;
  const u16* qpB = qb + ((long)qhi * 64 + wid * 16 + l16) * 3072;
  const bf16x8 qA0 = *reinterpret_cast<const bf16x8*>(qpA + g4 * 8);
  const bf16x8 qA1 = *reinterpret_cast<const bf16x8*>(qpA + 32 + g4 * 8);
  const bf16x8 qB0 = *reinterpret_cast<const bf16x8*>(qpB + g4 * 8);
  const bf16x8 qB1 = *reinterpret_cast<const bf16x8*>(qpB + 32 + g4 * 8);

  f32x4 accA[4] = {}, accB[4] = {};
  float mA = -3e38f, lA = 0.f, mB = -3e38f, lB = 0.f;
  const float cl = 0.125f * 1.4426950408889634f;  // scale * log2(e)

  // staging addresses
  const int krow = tid >> 3;                                    // 0..31
  const int scolE = (((tid & 7) * 16) ^ ((krow & 7) << 4)) >> 1;  // swizzled src col (elems)
  const int vkey = (lane & 31) * 2;
  const int vd = wid * 8 + (lane >> 5) * 32;
  const int kswz = (l16 & 7) << 4;

  u16x8 vv0, vv1;

  auto stage_issue = [&](int buf, int kt) {
    __builtin_amdgcn_global_load_lds((AS1 void*)(kb + (long)(kt * 64 + krow) * 3072 + scolE),
                                     (AS3 void*)(&Klds[buf][tid * 8]), 16, 0, 0);
    __builtin_amdgcn_global_load_lds((AS1 void*)(kb + (long)(kt * 64 + krow + 32) * 3072 + scolE),
                                     (AS3 void*)(&Klds[buf][2048 + tid * 8]), 16, 0, 0);
    const u16* gv = vb + (long)(kt * 64 + vkey) * 3072 + vd;
    vv0 = *reinterpret_cast<const u16x8*>(gv);
    vv1 = *reinterpret_cast<const u16x8*>(gv + 3072);
  };
  auto vt_write = [&](int buf) {
#pragma unroll
    for (int j = 0; j < 8; ++j)
      *reinterpret_cast<u32*>(&Vt[buf][(vd + j) * 72 + vkey]) =
          (u32)vv0[j] | ((u32)vv1[j] << 16);
  };

  auto tile_step = [&](f32x4* acc, float& m_r, float& l_r, const bf16x8& q0, const bf16x8& q1,
                       bool diag, int pslot, bf16x8 (&kf)[4][2], int cur) {
    // S^T = K Q^T : s[kn][j] = S[q=l16][key = kn*16 + g4*4 + j]
    f32x4 s[4];
#pragma unroll
    for (int kn = 0; kn < 4; ++kn) {
      f32x4 z = {0.f, 0.f, 0.f, 0.f};
      z = __builtin_amdgcn_mfma_f32_16x16x32_bf16(kf[kn][0], q0, z, 0, 0, 0);
      z = __builtin_amdgcn_mfma_f32_16x16x32_bf16(kf[kn][1], q1, z, 0, 0, 0);
      s[kn] = z;
    }
    if (diag) {
      const int qrel = wid * 16 + l16;
#pragma unroll
      for (int kn = 0; kn < 4; ++kn)
#pragma unroll
        for (int j = 0; j < 4; ++j)
          if (kn * 16 + g4 * 4 + j > qrel) s[kn][j] = -3e38f;
    }
    // online softmax: each lane owns q-row l16; reduce over g4 groups
    float mloc = fmaxf(fmaxf(fmaxf(s[0][0], s[0][1]), fmaxf(s[0][2], s[0][3])),
                       fmaxf(fmaxf(s[1][0], s[1][1]), fmaxf(s[1][2], s[1][3])));
    mloc = fmaxf(mloc, fmaxf(fmaxf(fmaxf(s[2][0], s[2][1]), fmaxf(s[2][2], s[2][3])),
                             fmaxf(fmaxf(s[3][0], s[3][1]), fmaxf(s[3][2], s[3][3]))));
    mloc = fmaxf(mloc, __shfl_xor(mloc, 16));
    mloc = fmaxf(mloc, __shfl_xor(mloc, 32));
    const float mnew = fmaxf(m_r, mloc);
    const float corr = exp2f((m_r - mnew) * cl);
    m_r = mnew;
    float sum = 0.f;
#pragma unroll
    for (int kn = 0; kn < 4; ++kn)
#pragma unroll
      for (int j = 0; j < 4; ++j) {
        const float e = exp2f((s[kn][j] - mnew) * cl);
        s[kn][j] = e;
        sum += e;
      }
    sum += __shfl_xor(sum, 16);
    sum += __shfl_xor(sum, 32);
    l_r = l_r * corr + sum;
    // P -> LDS (row q = l16, col = key)
    u16* pl = &Plds[wid][pslot][0];
#pragma unroll
    for (int kn = 0; kn < 4; ++kn)
#pragma unroll
      for (int j = 0; j < 4; ++j)
        pl[l16 * 72 + kn * 16 + g4 * 4 + j] = f2bf(s[kn][j]);
    // rescale O by corr (acc rows q = g4*4+j live across lanes; corr lives at lane l16=q)
    float cR[4];
#pragma unroll
    for (int j = 0; j < 4; ++j) cR[j] = __shfl(corr, g4 * 4 + j, 16);
#pragma unroll
    for (int n = 0; n < 4; ++n)
#pragma unroll
      for (int j = 0; j < 4; ++j) acc[n][j] *= cR[j];
    // O += P V (A = P rows l16=q, B = V^T rows = d)
    const bf16x8 pa0 = *reinterpret_cast<const bf16x8*>(&pl[l16 * 72 + g4 * 8]);
    const bf16x8 pa1 = *reinterpret_cast<const bf16x8*>(&pl[l16 * 72 + 32 + g4 * 8]);
#pragma unroll
    for (int n = 0; n < 4; ++n) {
      const bf16x8 b0 = *reinterpret_cast<const bf16x8*>(&Vt[cur][(n * 16 + l16) * 72 + g4 * 8]);
      const bf16x8 b1 =
          *reinterpret_cast<const bf16x8*>(&Vt[cur][(n * 16 + l16) * 72 + 32 + g4 * 8]);
      acc[n] = __builtin_amdgcn_mfma_f32_16x16x32_bf16(pa0, b0, acc[n], 0, 0, 0);
      acc[n] = __builtin_amdgcn_mfma_f32_16x16x32_bf16(pa1, b1, acc[n], 0, 0, 0);
    }
  };

  // prologue: stage tile 0
  stage_issue(0, 0);
  vt_write(0);
  __syncthreads();

  const int nt = qhi + 1;
  for (int kt = 0; kt < nt; ++kt) {
    const int cur = kt & 1, nxt = cur ^ 1;
    const bool pre = (kt + 1 < nt);
    if (pre) stage_issue(nxt, kt + 1);  // async: K via global_load_lds, V into regs

    // K fragments (A-operand: lane l16 = key-row, elems = d), shared by both tiles
    bf16x8 kf[4][2];
#pragma unroll
    for (int kn = 0; kn < 4; ++kn) {
      const int row = kn * 16 + l16;
      kf[kn][0] = *reinterpret_cast<const bf16x8*>(
          &Klds[cur][row * 64 + (((g4 * 16) ^ kswz) >> 1)]);
      kf[kn][1] = *reinterpret_cast<const bf16x8*>(
          &Klds[cur][row * 64 + (((64 + g4 * 16) ^ kswz) >> 1)]);
    }

    if (kt <= qlo) tile_step(accA, mA, lA, qA0, qA1, kt == qlo, 0, kf, cur);
    tile_step(accB, mB, lB, qB0, qB1, kt == qhi, 1, kf, cur);

    if (pre) vt_write(nxt);  // regs -> LDS[nxt]; safe: all waves past barrier read [cur]
    __syncthreads();
  }

  // epilogue
  const long obase = (long)(bh >> 4) * 2048 * 1024 + (bh & 15) * 64;
  auto epi = [&](f32x4* acc, float l_r, int qt) {
    float lR[4];
#pragma unroll
    for (int j = 0; j < 4; ++j) lR[j] = __shfl(l_r, g4 * 4 + j, 16);
    u16* op = o + obase + (long)(qt * 64 + wid * 16 + g4 * 4) * 1024;
#pragma unroll
    for (int n = 0; n < 4; ++n)
#pragma unroll
      for (int j = 0; j < 4; ++j)
        op[j * 1024 + n * 16 + l16] = f2bf(acc[n][j] / lR[j]);
  };
  epi(accA, lA, qlo);
  epi(accB, lB, qhi);
}

extern "C" void kernel_launch(void* const* d_in, const int* in_sizes, int n_in,
                              void* d_out, int out_size, void* d_ws, size_t ws_size,
                              hipStream_t stream) {
  const float* x = (const float*)d_in[0];
  // d_in[1] = mask (causal tril -- not needed)
  const float* w_qkv = (const float*)d_in[2];
  const float* w_fc = (const float*)d_in[3];
  const float* qw = (const float*)d_in[4];
  const float* kw = (const float*)d_in[5];
  // d_in[6] = subset_attention_size: with a causal mask the split is an identity.
  float* out = (float*)d_out;

  char* ws = (char*)d_ws;
  u16* xb    = (u16*)(ws);                   // 8 MB
  u16* wqkvb = (u16*)(ws + (8L << 20));      // 6 MB
  u16* wfcb  = (u16*)(ws + (14L << 20));     // 2 MB
  u16* qkv   = (u16*)(ws + (16L << 20));     // 24 MB
  u16* ob    = (u16*)(ws + (40L << 20));     // 8 MB

  cvt_f32_bf16<<<4096, 256, 0, stream>>>(x, xb, 4194304);
  cvt_f32_bf16<<<3072, 256, 0, stream>>>(w_qkv, wqkvb, 3145728);
  cvt_f32_bf16<<<1024, 256, 0, stream>>>(w_fc, wfcb, 1048576);

  gemm_bt<0><<<dim3(32, 24), 256, 0, stream>>>(xb, wqkvb, (void*)qkv, 3072, 1024);
  rmsnorm_qk<<<8192, 256, 0, stream>>>(qkv, qw, kw);
  attn_causal<<<dim3(16, 32), 256, 0, stream>>>(qkv, ob);
  gemm_bt<1><<<dim3(32, 8), 256, 0, stream>>>(ob, wfcb, (void*)out, 1024, 1024);
}

// Round 3
// 117.391 us; speedup vs baseline: 1.7822x; 1.1464x over previous
//
#include <hip/hip_runtime.h>

typedef __bf16 bf16x8 __attribute__((ext_vector_type(8)));
typedef __bf16 bf16x4 __attribute__((ext_vector_type(4)));
typedef float f32x4 __attribute__((ext_vector_type(4)));
typedef unsigned short u16;
typedef unsigned int u32;
typedef unsigned short u16x4 __attribute__((ext_vector_type(4)));
typedef unsigned short u16x8 __attribute__((ext_vector_type(8)));

#define AS1 __attribute__((address_space(1)))
#define AS3 __attribute__((address_space(3)))

__device__ __forceinline__ u16 f2bf(float f) {
  unsigned u = __builtin_bit_cast(unsigned, f);
  u += 0x7fffu + ((u >> 16) & 1u);
  return (u16)(u >> 16);
}
__device__ __forceinline__ float bf2f(u16 h) {
  unsigned u = ((unsigned)h) << 16;
  return __builtin_bit_cast(float, u);
}

// ---------------- fp32 -> bf16 convert (x, w_qkv, w_fc fused) ----------------
__global__ __launch_bounds__(256) void cvt_all(const float* __restrict__ x,
                                               const float* __restrict__ wq,
                                               const float* __restrict__ wf,
                                               u16* __restrict__ xb, u16* __restrict__ wqb,
                                               u16* __restrict__ wfb) {
  long i = ((long)blockIdx.x * 256 + threadIdx.x) * 4;
  const float* src;
  u16* dst;
  long off;
  if (i < 4194304L) {
    src = x; dst = xb; off = i;
  } else if (i < 7340032L) {
    src = wq; dst = wqb; off = i - 4194304L;
  } else {
    src = wf; dst = wfb; off = i - 7340032L;
  }
  float4 v = *reinterpret_cast<const float4*>(src + off);
  u16x4 o;
  o.x = f2bf(v.x); o.y = f2bf(v.y); o.z = f2bf(v.z); o.w = f2bf(v.w);
  *reinterpret_cast<u16x4*>(dst + off) = o;
}

// ---------------- GEMM: C[M][N] = A[M][K] * W[N][K]^T, 128x128 tile ----------------
__global__ __launch_bounds__(256, 2) void gemm_qkv(const u16* __restrict__ A,
                                                   const u16* __restrict__ W,
                                                   u16* __restrict__ C, int N, int K) {
  __shared__ __align__(16) u16 As[128 * 32];
  __shared__ __align__(16) u16 Bs[128 * 32];
  const int tid = threadIdx.x;
  const int lane = tid & 63;
  const int wid = tid >> 6;
  const int wm = wid >> 1, wn = wid & 1;
  const int l16 = lane & 15, g4 = lane >> 4;
  const long bm = blockIdx.x, bn = blockIdx.y;

  const int srow = tid >> 2;
  const int scol = (tid & 3) * 8;
  const u16* aA0 = A + (bm * 128 + srow) * (long)K + scol;
  const u16* aA1 = aA0 + 64 * (long)K;
  const u16* aW0 = W + (bn * 128 + srow) * (long)K + scol;
  const u16* aW1 = aW0 + 64 * (long)K;

  f32x4 acc[4][4] = {};

  for (int kt = 0; kt < K; kt += 32) {
    __builtin_amdgcn_global_load_lds((AS1 void*)(aA0 + kt), (AS3 void*)(&As[tid * 8]), 16, 0, 0);
    __builtin_amdgcn_global_load_lds((AS1 void*)(aA1 + kt), (AS3 void*)(&As[2048 + tid * 8]), 16, 0, 0);
    __builtin_amdgcn_global_load_lds((AS1 void*)(aW0 + kt), (AS3 void*)(&Bs[tid * 8]), 16, 0, 0);
    __builtin_amdgcn_global_load_lds((AS1 void*)(aW1 + kt), (AS3 void*)(&Bs[2048 + tid * 8]), 16, 0, 0);
    __syncthreads();
    bf16x8 af[4], bfr[4];
#pragma unroll
    for (int m = 0; m < 4; ++m)
      af[m] = *reinterpret_cast<const bf16x8*>(&As[(wm * 64 + m * 16 + l16) * 32 + g4 * 8]);
#pragma unroll
    for (int n = 0; n < 4; ++n)
      bfr[n] = *reinterpret_cast<const bf16x8*>(&Bs[(wn * 64 + n * 16 + l16) * 32 + g4 * 8]);
#pragma unroll
    for (int m = 0; m < 4; ++m)
#pragma unroll
      for (int n = 0; n < 4; ++n)
        acc[m][n] = __builtin_amdgcn_mfma_f32_16x16x32_bf16(af[m], bfr[n], acc[m][n], 0, 0, 0);
    __syncthreads();
  }

#pragma unroll
  for (int m = 0; m < 4; ++m)
#pragma unroll
    for (int n = 0; n < 4; ++n)
#pragma unroll
      for (int j = 0; j < 4; ++j) {
        long row = bm * 128 + wm * 64 + m * 16 + g4 * 4 + j;
        long col = bn * 128 + wn * 64 + n * 16 + l16;
        C[row * N + col] = f2bf(acc[m][n][j]);
      }
}

// ---------------- FC GEMM: 128x64 tile, fp32 out (512 blocks -> 2/CU) ----------------
__global__ __launch_bounds__(256, 2) void gemm_fc(const u16* __restrict__ A,
                                                  const u16* __restrict__ W,
                                                  float* __restrict__ C, int N, int K) {
  __shared__ __align__(16) u16 As[128 * 32];
  __shared__ __align__(16) u16 Bs[64 * 32];
  const int tid = threadIdx.x;
  const int lane = tid & 63;
  const int wid = tid >> 6;
  const int wm = wid >> 1, wn = wid & 1;
  const int l16 = lane & 15, g4 = lane >> 4;
  const long bm = blockIdx.x, bn = blockIdx.y;

  const int srow = tid >> 2;
  const int scol = (tid & 3) * 8;
  const u16* aA0 = A + (bm * 128 + srow) * (long)K + scol;
  const u16* aA1 = aA0 + 64 * (long)K;
  const u16* aW0 = W + (bn * 64 + srow) * (long)K + scol;

  f32x4 acc[4][2] = {};

  for (int kt = 0; kt < K; kt += 32) {
    __builtin_amdgcn_global_load_lds((AS1 void*)(aA0 + kt), (AS3 void*)(&As[tid * 8]), 16, 0, 0);
    __builtin_amdgcn_global_load_lds((AS1 void*)(aA1 + kt), (AS3 void*)(&As[2048 + tid * 8]), 16, 0, 0);
    __builtin_amdgcn_global_load_lds((AS1 void*)(aW0 + kt), (AS3 void*)(&Bs[tid * 8]), 16, 0, 0);
    __syncthreads();
    bf16x8 af[4], bfr[2];
#pragma unroll
    for (int m = 0; m < 4; ++m)
      af[m] = *reinterpret_cast<const bf16x8*>(&As[(wm * 64 + m * 16 + l16) * 32 + g4 * 8]);
#pragma unroll
    for (int n = 0; n < 2; ++n)
      bfr[n] = *reinterpret_cast<const bf16x8*>(&Bs[(wn * 32 + n * 16 + l16) * 32 + g4 * 8]);
#pragma unroll
    for (int m = 0; m < 4; ++m)
#pragma unroll
      for (int n = 0; n < 2; ++n)
        acc[m][n] = __builtin_amdgcn_mfma_f32_16x16x32_bf16(af[m], bfr[n], acc[m][n], 0, 0, 0);
    __syncthreads();
  }

#pragma unroll
  for (int m = 0; m < 4; ++m)
#pragma unroll
    for (int n = 0; n < 2; ++n)
#pragma unroll
      for (int j = 0; j < 4; ++j) {
        long row = bm * 128 + wm * 64 + m * 16 + g4 * 4 + j;
        long col = bn * 64 + wn * 32 + n * 16 + l16;
        C[row * N + col] = acc[m][n][j];
      }
}

// ---------------- RMSNorm on q,k head-groups of qkv (in place, bf16) ----------------
__global__ __launch_bounds__(256) void rmsnorm_qk(u16* __restrict__ qkv,
                                                  const float* __restrict__ qw,
                                                  const float* __restrict__ kw) {
  const int tid = threadIdx.x;
  const int l16 = tid & 15;
  const long row = (long)blockIdx.x * 16 + (tid >> 4);
  const int isK = row >= 65536;
  const long r = isK ? row - 65536 : row;
  const long bl = r >> 4;
  const int h = (int)(r & 15);
  u16* p = qkv + bl * 3072 + (isK ? 1024 : 0) + h * 64 + l16 * 4;
  u16x4 v = *reinterpret_cast<const u16x4*>(p);
  float f0 = bf2f(v.x), f1 = bf2f(v.y), f2 = bf2f(v.z), f3 = bf2f(v.w);
  float ss = f0 * f0 + f1 * f1 + f2 * f2 + f3 * f3;
  ss += __shfl_xor(ss, 1);
  ss += __shfl_xor(ss, 2);
  ss += __shfl_xor(ss, 4);
  ss += __shfl_xor(ss, 8);
  const float inv = rsqrtf(ss * (1.0f / 64.0f) + 1e-5f);
  const float* w = isK ? kw : qw;
  u16x4 o;
  o.x = f2bf(f0 * inv * w[l16 * 4 + 0]);
  o.y = f2bf(f1 * inv * w[l16 * 4 + 1]);
  o.z = f2bf(f2 * inv * w[l16 * 4 + 2]);
  o.w = f2bf(f3 * inv * w[l16 * 4 + 3]);
  *reinterpret_cast<u16x4*>(p) = o;
}

// ---------------- causal flash attention, paired q-tiles, STATIC-MAX softmax ----------
// After RMSNorm(weight=1): ||q||=||k||=8 exactly => |S| <= 8. Softmax is shift-invariant,
// so use fixed max m=8: P = exp2((S-8)*scale*log2e) in [0, 1.01]. No online max, no
// rescale, l-sum reduced once in the epilogue.
// All LDS tiles XOR-swizzled: byte-in-row ^= (row&7)<<4 (conflict-free b128/b64/b32).
__global__ __launch_bounds__(256, 2) void attn_causal(const u16* __restrict__ qkv,
                                                      u16* __restrict__ o) {
  __shared__ __align__(16) u16 Klds[2][4096];  // [key=64][d=64], source-swizzled
  __shared__ __align__(16) u16 Vt[2][4096];    // [d=64][key=64], XOR-swizzled
  __shared__ __align__(16) u16 Plds[4][1024];  // per-wave [q=16][key=64], XOR-swizzled

  const int tid = threadIdx.x, lane = tid & 63, wid = tid >> 6;
  const int l16 = lane & 15, g4 = lane >> 4;
  const int h8 = (l16 & 7) << 4;  // read-side XOR (row & 7) << 4 for rows == l16 (mod 8)
  const int qlo = blockIdx.x, qhi = 31 - qlo;
  const int bh = blockIdx.y;
  const long base = (long)(bh >> 4) * 2048 * 3072 + (bh & 15) * 64;
  const u16* qb = qkv + base;
  const u16* kb = qkv + base + 1024;
  const u16* vb = qkv + base + 2048;

  // Q fragments (B-operand: lane l16 = q-row, elems = d)
  const u16* qpA = qb + ((long)qlo * 64 + wid * 16 + l16) * 3072;
  const u16* qpB = qb + ((long)qhi * 64 + wid * 16 + l16) * 3072;
  const bf16x8 qA0 = *reinterpret_cast<const bf16x8*>(qpA + g4 * 8);
  const bf16x8 qA1 = *reinterpret_cast<const bf16x8*>(qpA + 32 + g4 * 8);
  const bf16x8 qB0 = *reinterpret_cast<const bf16x8*>(qpB + g4 * 8);
  const bf16x8 qB1 = *reinterpret_cast<const bf16x8*>(qpB + 32 + g4 * 8);

  f32x4 accA[4] = {}, accB[4] = {};
  f32x4 laccA = {}, laccB = {};
  const float cl = 0.125f * 1.4426950408889634f;  // scale * log2(e)
  const float mc = -8.0f * cl;                    // -(static max)*scale*log2e

  // staging addresses
  const int krow = tid >> 3;                                      // 0..31
  const int scolE = (((tid & 7) * 16) ^ ((krow & 7) << 4)) >> 1;  // swizzled src col (elems)
  const int vkey = (lane & 31) * 2;
  const int vd = wid * 8 + (lane >> 5) * 32;

  u16x8 vv0, vv1;

  auto stage_issue = [&](int buf, int kt) {
    __builtin_amdgcn_global_load_lds((AS1 void*)(kb + (long)(kt * 64 + krow) * 3072 + scolE),
                                     (AS3 void*)(&Klds[buf][tid * 8]), 16, 0, 0);
    __builtin_amdgcn_global_load_lds((AS1 void*)(kb + (long)(kt * 64 + krow + 32) * 3072 + scolE),
                                     (AS3 void*)(&Klds[buf][2048 + tid * 8]), 16, 0, 0);
    const u16* gv = vb + (long)(kt * 64 + vkey) * 3072 + vd;
    vv0 = *reinterpret_cast<const u16x8*>(gv);
    vv1 = *reinterpret_cast<const u16x8*>(gv + 3072);
  };
  auto vt_write = [&](int buf) {
#pragma unroll
    for (int j = 0; j < 8; ++j) {
      const int r = vd + j;
      const int boff = (vkey * 2) ^ ((r & 7) << 4);
      *reinterpret_cast<u32*>(&Vt[buf][r * 64 + (boff >> 1)]) =
          (u32)vv0[j] | ((u32)vv1[j] << 16);
    }
  };

  auto tile_step = [&](f32x4* acc, f32x4& lacc, const bf16x8& q0, const bf16x8& q1, bool diag,
                       bf16x8 (&kf)[4][2], int cur) {
    // S^T = K Q^T : s[kn][j] = S[q=l16][key = kn*16 + g4*4 + j]
    f32x4 s[4];
    __builtin_amdgcn_s_setprio(1);
#pragma unroll
    for (int kn = 0; kn < 4; ++kn) {
      f32x4 z = {0.f, 0.f, 0.f, 0.f};
      z = __builtin_amdgcn_mfma_f32_16x16x32_bf16(kf[kn][0], q0, z, 0, 0, 0);
      z = __builtin_amdgcn_mfma_f32_16x16x32_bf16(kf[kn][1], q1, z, 0, 0, 0);
      s[kn] = z;
    }
    __builtin_amdgcn_s_setprio(0);
    if (diag) {
      const int qrel = wid * 16 + l16;
#pragma unroll
      for (int kn = 0; kn < 4; ++kn)
#pragma unroll
        for (int j = 0; j < 4; ++j)
          if (kn * 16 + g4 * 4 + j > qrel) s[kn][j] = -3e38f;
    }
    // static-max softmax: P = exp2(S*cl + mc), masked -> 0
#pragma unroll
    for (int kn = 0; kn < 4; ++kn) {
#pragma unroll
      for (int j = 0; j < 4; ++j) s[kn][j] = exp2f(fmaf(s[kn][j], cl, mc));
      lacc += s[kn];
    }
    // P -> LDS, b64-packed, swizzled: row l16, keys kn*16+g4*4..+3
    u16* pl = &Plds[wid][0];
#pragma unroll
    for (int kn = 0; kn < 4; ++kn) {
      bf16x4 w;
      w[0] = (__bf16)s[kn][0];
      w[1] = (__bf16)s[kn][1];
      w[2] = (__bf16)s[kn][2];
      w[3] = (__bf16)s[kn][3];
      const int boff = (kn * 32 + g4 * 8) ^ h8;
      *reinterpret_cast<bf16x4*>(&pl[l16 * 64 + (boff >> 1)]) = w;
    }
    // O += P V (A = P rows l16=q, B = V^T rows = d)
    const bf16x8 pa0 = *reinterpret_cast<const bf16x8*>(&pl[l16 * 64 + (((0 * 64 + g4 * 16) ^ h8) >> 1)]);
    const bf16x8 pa1 = *reinterpret_cast<const bf16x8*>(&pl[l16 * 64 + (((1 * 64 + g4 * 16) ^ h8) >> 1)]);
    __builtin_amdgcn_s_setprio(1);
#pragma unroll
    for (int n = 0; n < 4; ++n) {
      const int rr = n * 16 + l16;
      const bf16x8 b0 =
          *reinterpret_cast<const bf16x8*>(&Vt[cur][rr * 64 + (((0 * 64 + g4 * 16) ^ h8) >> 1)]);
      const bf16x8 b1 =
          *reinterpret_cast<const bf16x8*>(&Vt[cur][rr * 64 + (((1 * 64 + g4 * 16) ^ h8) >> 1)]);
      acc[n] = __builtin_amdgcn_mfma_f32_16x16x32_bf16(pa0, b0, acc[n], 0, 0, 0);
      acc[n] = __builtin_amdgcn_mfma_f32_16x16x32_bf16(pa1, b1, acc[n], 0, 0, 0);
    }
    __builtin_amdgcn_s_setprio(0);
  };

  // prologue: stage tile 0
  stage_issue(0, 0);
  vt_write(0);
  __syncthreads();

  const int nt = qhi + 1;
  for (int kt = 0; kt < nt; ++kt) {
    const int cur = kt & 1, nxt = cur ^ 1;
    const bool pre = (kt + 1 < nt);
    if (pre) stage_issue(nxt, kt + 1);  // async: K via global_load_lds, V into regs

    // K fragments (A-operand: lane l16 = key-row, elems = d), shared by both q-tiles
    bf16x8 kf[4][2];
#pragma unroll
    for (int kn = 0; kn < 4; ++kn) {
      const int row = kn * 16 + l16;
      kf[kn][0] = *reinterpret_cast<const bf16x8*>(&Klds[cur][row * 64 + (((g4 * 16) ^ h8) >> 1)]);
      kf[kn][1] =
          *reinterpret_cast<const bf16x8*>(&Klds[cur][row * 64 + (((64 + g4 * 16) ^ h8) >> 1)]);
    }

    if (kt <= qlo) tile_step(accA, laccA, qA0, qA1, kt == qlo, kf, cur);
    tile_step(accB, laccB, qB0, qB1, kt == qhi, kf, cur);

    if (pre) vt_write(nxt);  // regs -> LDS[nxt]; safe: all waves past barrier read [cur]
    __syncthreads();
  }

  // epilogue
  const long obase = (long)(bh >> 4) * 2048 * 1024 + (bh & 15) * 64;
  auto epi = [&](f32x4* acc, f32x4 lacc, int qt) {
    float l = lacc[0] + lacc[1] + lacc[2] + lacc[3];
    l += __shfl_xor(l, 16);
    l += __shfl_xor(l, 32);
    float lR[4];
#pragma unroll
    for (int j = 0; j < 4; ++j) lR[j] = __shfl(l, g4 * 4 + j, 16);
    u16* op = o + obase + (long)(qt * 64 + wid * 16 + g4 * 4) * 1024;
#pragma unroll
    for (int n = 0; n < 4; ++n)
#pragma unroll
      for (int j = 0; j < 4; ++j)
        op[j * 1024 + n * 16 + l16] = f2bf(acc[n][j] / lR[j]);
  };
  epi(accA, laccA, qlo);
  epi(accB, laccB, qhi);
}

extern "C" void kernel_launch(void* const* d_in, const int* in_sizes, int n_in,
                              void* d_out, int out_size, void* d_ws, size_t ws_size,
                              hipStream_t stream) {
  const float* x = (const float*)d_in[0];
  // d_in[1] = mask (causal tril -- not needed)
  const float* w_qkv = (const float*)d_in[2];
  const float* w_fc = (const float*)d_in[3];
  const float* qw = (const float*)d_in[4];
  const float* kw = (const float*)d_in[5];
  // d_in[6] = subset_attention_size: with a causal mask the split is an identity.
  float* out = (float*)d_out;

  char* ws = (char*)d_ws;
  u16* xb    = (u16*)(ws);                   // 8 MB
  u16* wqkvb = (u16*)(ws + (8L << 20));      // 6 MB
  u16* wfcb  = (u16*)(ws + (14L << 20));     // 2 MB
  u16* qkv   = (u16*)(ws + (16L << 20));     // 24 MB
  u16* ob    = (u16*)(ws + (40L << 20));     // 8 MB

  cvt_all<<<8192, 256, 0, stream>>>(x, w_qkv, w_fc, xb, wqkvb, wfcb);

  gemm_qkv<<<dim3(32, 24), 256, 0, stream>>>(xb, wqkvb, qkv, 3072, 1024);
  rmsnorm_qk<<<8192, 256, 0, stream>>>(qkv, qw, kw);
  attn_causal<<<dim3(16, 32), 256, 0, stream>>>(qkv, ob);
  gemm_fc<<<dim3(32, 16), 256, 0, stream>>>(ob, wfcb, out, 1024, 1024);
}

// Round 4
// 115.735 us; speedup vs baseline: 1.8077x; 1.0143x over previous
//
#include <hip/hip_runtime.h>

typedef __bf16 bf16x8 __attribute__((ext_vector_type(8)));
typedef __bf16 bf16x4 __attribute__((ext_vector_type(4)));
typedef float f32x4 __attribute__((ext_vector_type(4)));
typedef unsigned short u16;
typedef unsigned int u32;
typedef unsigned short u16x4 __attribute__((ext_vector_type(4)));
typedef unsigned short u16x8 __attribute__((ext_vector_type(8)));

#define AS1 __attribute__((address_space(1)))
#define AS3 __attribute__((address_space(3)))

__device__ __forceinline__ u16 f2bf(float f) {
  unsigned u = __builtin_bit_cast(unsigned, f);
  u += 0x7fffu + ((u >> 16) & 1u);
  return (u16)(u >> 16);
}

// ---------------- fp32 -> bf16 convert (x, w_qkv, w_fc fused) ----------------
__global__ __launch_bounds__(256) void cvt_all(const float* __restrict__ x,
                                               const float* __restrict__ wq,
                                               const float* __restrict__ wf,
                                               u16* __restrict__ xb, u16* __restrict__ wqb,
                                               u16* __restrict__ wfb) {
  long i = ((long)blockIdx.x * 256 + threadIdx.x) * 4;
  const float* src;
  u16* dst;
  long off;
  if (i < 4194304L) {
    src = x; dst = xb; off = i;
  } else if (i < 7340032L) {
    src = wq; dst = wqb; off = i - 4194304L;
  } else {
    src = wf; dst = wfb; off = i - 7340032L;
  }
  float4 v = *reinterpret_cast<const float4*>(src + off);
  u16x4 o;
  o.x = f2bf(v.x); o.y = f2bf(v.y); o.z = f2bf(v.z); o.w = f2bf(v.w);
  *reinterpret_cast<u16x4*>(dst + off) = o;
}

// -------- QKV GEMM: C[4096][3072] = X[4096][1024] * W[3072][1024]^T, RMS fused -------
// RMS: head = 64 cols; per wave cols span wn*64..wn*64+63 (head-aligned). For fixed
// (m, j) the 64 cols live in acc[m][0..3][j] across the 16 lanes of an l16-group.
__global__ __launch_bounds__(256, 2) void gemm_qkv(const u16* __restrict__ A,
                                                   const u16* __restrict__ W,
                                                   u16* __restrict__ C,
                                                   const float* __restrict__ qw,
                                                   const float* __restrict__ kw) {
  constexpr int N = 3072, K = 1024;
  __shared__ __align__(16) u16 As[128 * 32];
  __shared__ __align__(16) u16 Bs[128 * 32];
  const int tid = threadIdx.x;
  const int lane = tid & 63;
  const int wid = tid >> 6;
  const int wm = wid >> 1, wn = wid & 1;
  const int l16 = lane & 15, g4 = lane >> 4;
  const long bm = blockIdx.x, bn = blockIdx.y;

  const int srow = tid >> 2;
  const int scol = (tid & 3) * 8;
  const u16* aA0 = A + (bm * 128 + srow) * (long)K + scol;
  const u16* aA1 = aA0 + 64 * (long)K;
  const u16* aW0 = W + (bn * 128 + srow) * (long)K + scol;
  const u16* aW1 = aW0 + 64 * (long)K;

  f32x4 acc[4][4] = {};

  for (int kt = 0; kt < K; kt += 32) {
    __builtin_amdgcn_global_load_lds((AS1 void*)(aA0 + kt), (AS3 void*)(&As[tid * 8]), 16, 0, 0);
    __builtin_amdgcn_global_load_lds((AS1 void*)(aA1 + kt), (AS3 void*)(&As[2048 + tid * 8]), 16, 0, 0);
    __builtin_amdgcn_global_load_lds((AS1 void*)(aW0 + kt), (AS3 void*)(&Bs[tid * 8]), 16, 0, 0);
    __builtin_amdgcn_global_load_lds((AS1 void*)(aW1 + kt), (AS3 void*)(&Bs[2048 + tid * 8]), 16, 0, 0);
    __syncthreads();
    bf16x8 af[4], bfr[4];
#pragma unroll
    for (int m = 0; m < 4; ++m)
      af[m] = *reinterpret_cast<const bf16x8*>(&As[(wm * 64 + m * 16 + l16) * 32 + g4 * 8]);
#pragma unroll
    for (int n = 0; n < 4; ++n)
      bfr[n] = *reinterpret_cast<const bf16x8*>(&Bs[(wn * 64 + n * 16 + l16) * 32 + g4 * 8]);
#pragma unroll
    for (int m = 0; m < 4; ++m)
#pragma unroll
      for (int n = 0; n < 4; ++n)
        acc[m][n] = __builtin_amdgcn_mfma_f32_16x16x32_bf16(af[m], bfr[n], acc[m][n], 0, 0, 0);
    __syncthreads();
  }

  // fused per-head RMSNorm for q (bn<8) and k (8<=bn<16) columns
  if (bn < 16) {
    const float* w = (bn < 8) ? qw : kw;
    float wv[4];
#pragma unroll
    for (int n = 0; n < 4; ++n) wv[n] = w[n * 16 + l16];
#pragma unroll
    for (int m = 0; m < 4; ++m) {
#pragma unroll
      for (int j = 0; j < 4; ++j) {
        float ss = 0.f;
#pragma unroll
        for (int n = 0; n < 4; ++n) ss = fmaf(acc[m][n][j], acc[m][n][j], ss);
        ss += __shfl_xor(ss, 1);
        ss += __shfl_xor(ss, 2);
        ss += __shfl_xor(ss, 4);
        ss += __shfl_xor(ss, 8);
        const float inv = rsqrtf(ss * (1.0f / 64.0f) + 1e-5f);
#pragma unroll
        for (int n = 0; n < 4; ++n) acc[m][n][j] *= inv * wv[n];
      }
    }
  }

#pragma unroll
  for (int m = 0; m < 4; ++m)
#pragma unroll
    for (int n = 0; n < 4; ++n)
#pragma unroll
      for (int j = 0; j < 4; ++j) {
        long row = bm * 128 + wm * 64 + m * 16 + g4 * 4 + j;
        long col = bn * 128 + wn * 64 + n * 16 + l16;
        C[row * N + col] = f2bf(acc[m][n][j]);
      }
}

// ---------------- FC GEMM: 128x64 tile, fp32 out ----------------
__global__ __launch_bounds__(256, 2) void gemm_fc(const u16* __restrict__ A,
                                                  const u16* __restrict__ W,
                                                  float* __restrict__ C) {
  constexpr int N = 1024, K = 1024;
  __shared__ __align__(16) u16 As[128 * 32];
  __shared__ __align__(16) u16 Bs[64 * 32];
  const int tid = threadIdx.x;
  const int lane = tid & 63;
  const int wid = tid >> 6;
  const int wm = wid >> 1, wn = wid & 1;
  const int l16 = lane & 15, g4 = lane >> 4;
  const long bm = blockIdx.x, bn = blockIdx.y;

  const int srow = tid >> 2;
  const int scol = (tid & 3) * 8;
  const u16* aA0 = A + (bm * 128 + srow) * (long)K + scol;
  const u16* aA1 = aA0 + 64 * (long)K;
  const u16* aW0 = W + (bn * 64 + srow) * (long)K + scol;

  f32x4 acc[4][2] = {};

  for (int kt = 0; kt < K; kt += 32) {
    __builtin_amdgcn_global_load_lds((AS1 void*)(aA0 + kt), (AS3 void*)(&As[tid * 8]), 16, 0, 0);
    __builtin_amdgcn_global_load_lds((AS1 void*)(aA1 + kt), (AS3 void*)(&As[2048 + tid * 8]), 16, 0, 0);
    __builtin_amdgcn_global_load_lds((AS1 void*)(aW0 + kt), (AS3 void*)(&Bs[tid * 8]), 16, 0, 0);
    __syncthreads();
    bf16x8 af[4], bfr[2];
#pragma unroll
    for (int m = 0; m < 4; ++m)
      af[m] = *reinterpret_cast<const bf16x8*>(&As[(wm * 64 + m * 16 + l16) * 32 + g4 * 8]);
#pragma unroll
    for (int n = 0; n < 2; ++n)
      bfr[n] = *reinterpret_cast<const bf16x8*>(&Bs[(wn * 32 + n * 16 + l16) * 32 + g4 * 8]);
#pragma unroll
    for (int m = 0; m < 4; ++m)
#pragma unroll
      for (int n = 0; n < 2; ++n)
        acc[m][n] = __builtin_amdgcn_mfma_f32_16x16x32_bf16(af[m], bfr[n], acc[m][n], 0, 0, 0);
    __syncthreads();
  }

#pragma unroll
  for (int m = 0; m < 4; ++m)
#pragma unroll
    for (int n = 0; n < 2; ++n)
#pragma unroll
      for (int j = 0; j < 4; ++j) {
        long row = bm * 128 + wm * 64 + m * 16 + g4 * 4 + j;
        long col = bn * 64 + wn * 32 + n * 16 + l16;
        C[row * N + col] = acc[m][n][j];
      }
}

// ---- causal flash attention: QBLK=32 pairs (i,63-i), wave = (row-half x key-half) ----
// grid 1024 (XCD-chunked: xcd = f&7 hosts bh 4*xcd..4*xcd+3). 4 waves: rh=wid&1 (16 q-rows),
// kh=wid>>1 (32 keys). Static-max softmax (||q||=||k||=8 => |S|<=8) makes key-half partial
// (O,l) additive: combined once at the end through LDS. Step skipped when 2kt+kh > i.
__global__ __launch_bounds__(256, 4) void attn_causal(const u16* __restrict__ qkv,
                                                      u16* __restrict__ o) {
  __shared__ __align__(16) u16 Klds[2][4096];  // [key=64][d=64], source-swizzled
  __shared__ __align__(16) u16 Vt[2][4096];    // [d=64][key=64], XOR-swizzled
  __shared__ __align__(16) u16 Plds[4][640];   // per wave [q=16][40] (32 used, pad 8)

  const int tid = threadIdx.x, lane = tid & 63, wid = tid >> 6;
  const int l16 = lane & 15, g4 = lane >> 4;
  const int rh = wid & 1, kh = wid >> 1;

  const int f = blockIdx.x;
  const int kk = f >> 3;
  const int bh = (f & 7) * 4 + (kk >> 5);
  const int i = kk & 31;
  const int iA = i, iB = 63 - i;

  const long base = (long)(bh >> 4) * 2048 * 3072 + (bh & 15) * 64;
  const u16* qb = qkv + base;
  const u16* kb = qkv + base + 1024;
  const u16* vb = qkv + base + 2048;

  const u16* qpA = qb + ((long)iA * 32 + rh * 16 + l16) * 3072;
  const u16* qpB = qb + ((long)iB * 32 + rh * 16 + l16) * 3072;
  const bf16x8 qA0 = *reinterpret_cast<const bf16x8*>(qpA + g4 * 8);
  const bf16x8 qA1 = *reinterpret_cast<const bf16x8*>(qpA + 32 + g4 * 8);
  const bf16x8 qB0 = *reinterpret_cast<const bf16x8*>(qpB + g4 * 8);
  const bf16x8 qB1 = *reinterpret_cast<const bf16x8*>(qpB + 32 + g4 * 8);

  f32x4 accA[4] = {}, accB[4] = {};
  f32x4 laccA = {}, laccB = {};
  const float cl = 0.125f * 1.4426950408889634f;  // scale * log2(e)
  const float mc = -8.0f * cl;                    // static max = 8

  const int krow = tid >> 3;
  const int scolE = (((tid & 7) * 16) ^ ((krow & 7) << 4)) >> 1;
  const int vkey = (lane & 31) * 2;
  const int vd = wid * 8 + (lane >> 5) * 32;
  u16x8 vv0, vv1;

  auto stage_issue = [&](int buf, int kt) {
    __builtin_amdgcn_global_load_lds((AS1 void*)(kb + (long)(kt * 64 + krow) * 3072 + scolE),
                                     (AS3 void*)(&Klds[buf][tid * 8]), 16, 0, 0);
    __builtin_amdgcn_global_load_lds((AS1 void*)(kb + (long)(kt * 64 + krow + 32) * 3072 + scolE),
                                     (AS3 void*)(&Klds[buf][2048 + tid * 8]), 16, 0, 0);
    const u16* gv = vb + (long)(kt * 64 + vkey) * 3072 + vd;
    vv0 = *reinterpret_cast<const u16x8*>(gv);
    vv1 = *reinterpret_cast<const u16x8*>(gv + 3072);
  };
  auto vt_write = [&](int buf) {
#pragma unroll
    for (int j = 0; j < 8; ++j) {
      const int r = vd + j;
      const int boff = (vkey * 2) ^ ((r & 7) << 4);
      *reinterpret_cast<u32*>(&Vt[buf][r * 64 + (boff >> 1)]) =
          (u32)vv0[j] | ((u32)vv1[j] << 16);
    }
  };

  auto step = [&](int qt, f32x4* acc, f32x4& lacc, const bf16x8& q0, const bf16x8& q1,
                  bf16x8 (&kf)[2][2], int cur, int kt) {
    const int dd = qt - 2 * kt - kh;
    if (dd < 0) return;  // wave-uniform: all keys masked
    f32x4 s[2];
    __builtin_amdgcn_s_setprio(1);
#pragma unroll
    for (int kn = 0; kn < 2; ++kn) {
      f32x4 z = {0.f, 0.f, 0.f, 0.f};
      z = __builtin_amdgcn_mfma_f32_16x16x32_bf16(kf[kn][0], q0, z, 0, 0, 0);
      z = __builtin_amdgcn_mfma_f32_16x16x32_bf16(kf[kn][1], q1, z, 0, 0, 0);
      s[kn] = z;
    }
    __builtin_amdgcn_s_setprio(0);
    if (dd == 0) {  // diagonal sub-block: mask key_local > q_local
      const int qr = rh * 16 + l16;
#pragma unroll
      for (int kn = 0; kn < 2; ++kn)
#pragma unroll
        for (int j = 0; j < 4; ++j)
          if (kn * 16 + g4 * 4 + j > qr) s[kn][j] = -3e38f;
    }
#pragma unroll
    for (int kn = 0; kn < 2; ++kn) {
#pragma unroll
      for (int j = 0; j < 4; ++j) s[kn][j] = exp2f(fmaf(s[kn][j], cl, mc));
      lacc += s[kn];
    }
    u16* pl = &Plds[wid][0];
#pragma unroll
    for (int kn = 0; kn < 2; ++kn) {
      bf16x4 w4;
      w4[0] = (__bf16)s[kn][0];
      w4[1] = (__bf16)s[kn][1];
      w4[2] = (__bf16)s[kn][2];
      w4[3] = (__bf16)s[kn][3];
      *reinterpret_cast<bf16x4*>(&pl[l16 * 40 + kn * 16 + g4 * 4]) = w4;
    }
    const bf16x8 pa = *reinterpret_cast<const bf16x8*>(&pl[l16 * 40 + g4 * 8]);
    __builtin_amdgcn_s_setprio(1);
#pragma unroll
    for (int n = 0; n < 4; ++n) {
      const int rr = n * 16 + l16;
      const bf16x8 b = *reinterpret_cast<const bf16x8*>(
          &Vt[cur][rr * 64 + (((kh * 64 + g4 * 16) ^ ((rr & 7) << 4)) >> 1)]);
      acc[n] = __builtin_amdgcn_mfma_f32_16x16x32_bf16(pa, b, acc[n], 0, 0, 0);
    }
    __builtin_amdgcn_s_setprio(0);
  };

  stage_issue(0, 0);
  vt_write(0);
  __syncthreads();

  const int ktmax = (iB >> 1) + 1;
  for (int kt = 0; kt < ktmax; ++kt) {
    const int cur = kt & 1, nxt = cur ^ 1;
    const bool pre = (kt + 1 < ktmax);
    if (pre) stage_issue(nxt, kt + 1);

    bf16x8 kf[2][2];
#pragma unroll
    for (int kn = 0; kn < 2; ++kn) {
      const int row = kh * 32 + kn * 16 + l16;
#pragma unroll
      for (int ck = 0; ck < 2; ++ck)
        kf[kn][ck] = *reinterpret_cast<const bf16x8*>(
            &Klds[cur][row * 64 + (((ck * 64 + g4 * 16) ^ ((l16 & 7) << 4)) >> 1)]);
    }

    step(iA, accA, laccA, qA0, qA1, kf, cur, kt);
    step(iB, accB, laccB, qB0, qB1, kf, cur, kt);

    if (pre) vt_write(nxt);
    __syncthreads();
  }

  // ---- combine the two key-halves (additive thanks to static max) ----
  auto lred = [&](const f32x4& v) {
    float l = v[0] + v[1] + v[2] + v[3];
    l += __shfl_xor(l, 16);
    l += __shfl_xor(l, 32);
    return l;
  };
  float lA = lred(laccA), lB = lred(laccB);

  float* cbf = reinterpret_cast<float*>(&Klds[0][0]);  // [2][8][256] f32
  float* lvf = reinterpret_cast<float*>(&Vt[0][0]);    // [2][2][64] f32
  if (kh == 1) {
#pragma unroll
    for (int n = 0; n < 4; ++n) {
      *reinterpret_cast<f32x4*>(&cbf[(rh * 8 + n) * 256 + lane * 4]) = accA[n];
      *reinterpret_cast<f32x4*>(&cbf[(rh * 8 + 4 + n) * 256 + lane * 4]) = accB[n];
    }
    lvf[(rh * 2 + 0) * 64 + lane] = lA;
    lvf[(rh * 2 + 1) * 64 + lane] = lB;
  }
  __syncthreads();
  if (kh == 0) {
#pragma unroll
    for (int n = 0; n < 4; ++n) {
      accA[n] += *reinterpret_cast<const f32x4*>(&cbf[(rh * 8 + n) * 256 + lane * 4]);
      accB[n] += *reinterpret_cast<const f32x4*>(&cbf[(rh * 8 + 4 + n) * 256 + lane * 4]);
    }
    lA += lvf[(rh * 2 + 0) * 64 + lane];
    lB += lvf[(rh * 2 + 1) * 64 + lane];

    const long obase = (long)(bh >> 4) * 2048 * 1024 + (bh & 15) * 64;
    auto epi = [&](f32x4* acc, float l, int qt) {
      float lR[4];
#pragma unroll
      for (int j = 0; j < 4; ++j) lR[j] = __shfl(l, g4 * 4 + j, 16);
      u16* op = o + obase + ((long)qt * 32 + rh * 16 + g4 * 4) * 1024;
#pragma unroll
      for (int n = 0; n < 4; ++n)
#pragma unroll
        for (int j = 0; j < 4; ++j)
          op[j * 1024 + n * 16 + l16] = f2bf(acc[n][j] / lR[j]);
    };
    epi(accA, lA, iA);
    epi(accB, lB, iB);
  }
}

extern "C" void kernel_launch(void* const* d_in, const int* in_sizes, int n_in,
                              void* d_out, int out_size, void* d_ws, size_t ws_size,
                              hipStream_t stream) {
  const float* x = (const float*)d_in[0];
  // d_in[1] = mask (causal tril -- not needed)
  const float* w_qkv = (const float*)d_in[2];
  const float* w_fc = (const float*)d_in[3];
  const float* qw = (const float*)d_in[4];
  const float* kw = (const float*)d_in[5];
  // d_in[6] = subset_attention_size: with a causal mask the split is an identity.
  float* out = (float*)d_out;

  char* ws = (char*)d_ws;
  u16* xb    = (u16*)(ws);                   // 8 MB
  u16* wqkvb = (u16*)(ws + (8L << 20));      // 6 MB
  u16* wfcb  = (u16*)(ws + (14L << 20));     // 2 MB
  u16* qkv   = (u16*)(ws + (16L << 20));     // 24 MB
  u16* ob    = (u16*)(ws + (40L << 20));     // 8 MB

  cvt_all<<<8192, 256, 0, stream>>>(x, w_qkv, w_fc, xb, wqkvb, wfcb);
  gemm_qkv<<<dim3(32, 24), 256, 0, stream>>>(xb, wqkvb, qkv, qw, kw);
  attn_causal<<<1024, 256, 0, stream>>>(qkv, ob);
  gemm_fc<<<dim3(32, 16), 256, 0, stream>>>(ob, wfcb, out);
}

// Round 5
// 113.477 us; speedup vs baseline: 1.8437x; 1.0199x over previous
//
#include <hip/hip_runtime.h>

typedef __bf16 bf16x8 __attribute__((ext_vector_type(8)));
typedef __bf16 bf16x4 __attribute__((ext_vector_type(4)));
typedef float f32x4 __attribute__((ext_vector_type(4)));
typedef unsigned short u16;
typedef unsigned int u32;
typedef unsigned short u16x4 __attribute__((ext_vector_type(4)));
typedef unsigned short u16x8 __attribute__((ext_vector_type(8)));

#define AS1 __attribute__((address_space(1)))
#define AS3 __attribute__((address_space(3)))

__device__ __forceinline__ u16 f2bf(float f) {
  unsigned u = __builtin_bit_cast(unsigned, f);
  u += 0x7fffu + ((u >> 16) & 1u);
  return (u16)(u >> 16);
}

// ---------------- fp32 -> bf16 convert (x, w_qkv, w_fc fused) ----------------
__global__ __launch_bounds__(256) void cvt_all(const float* __restrict__ x,
                                               const float* __restrict__ wq,
                                               const float* __restrict__ wf,
                                               u16* __restrict__ xb, u16* __restrict__ wqb,
                                               u16* __restrict__ wfb) {
  long i = ((long)blockIdx.x * 256 + threadIdx.x) * 4;
  const float* src;
  u16* dst;
  long off;
  if (i < 4194304L) {
    src = x; dst = xb; off = i;
  } else if (i < 7340032L) {
    src = wq; dst = wqb; off = i - 4194304L;
  } else {
    src = wf; dst = wfb; off = i - 7340032L;
  }
  float4 v = *reinterpret_cast<const float4*>(src + off);
  u16x4 o;
  o.x = f2bf(v.x); o.y = f2bf(v.y); o.z = f2bf(v.z); o.w = f2bf(v.w);
  *reinterpret_cast<u16x4*>(dst + off) = o;
}

// -------- QKV GEMM: C[4096][3072] = X[4096][1024] * W[3072][1024]^T, RMS fused -------
__global__ __launch_bounds__(256, 2) void gemm_qkv(const u16* __restrict__ A,
                                                   const u16* __restrict__ W,
                                                   u16* __restrict__ C,
                                                   const float* __restrict__ qw,
                                                   const float* __restrict__ kw) {
  constexpr int N = 3072, K = 1024;
  __shared__ __align__(16) u16 As[128 * 32];
  __shared__ __align__(16) u16 Bs[128 * 32];
  const int tid = threadIdx.x;
  const int lane = tid & 63;
  const int wid = tid >> 6;
  const int wm = wid >> 1, wn = wid & 1;
  const int l16 = lane & 15, g4 = lane >> 4;
  const long bm = blockIdx.x, bn = blockIdx.y;

  const int srow = tid >> 2;
  const int scol = (tid & 3) * 8;
  const u16* aA0 = A + (bm * 128 + srow) * (long)K + scol;
  const u16* aA1 = aA0 + 64 * (long)K;
  const u16* aW0 = W + (bn * 128 + srow) * (long)K + scol;
  const u16* aW1 = aW0 + 64 * (long)K;

  f32x4 acc[4][4] = {};

  for (int kt = 0; kt < K; kt += 32) {
    __builtin_amdgcn_global_load_lds((AS1 void*)(aA0 + kt), (AS3 void*)(&As[tid * 8]), 16, 0, 0);
    __builtin_amdgcn_global_load_lds((AS1 void*)(aA1 + kt), (AS3 void*)(&As[2048 + tid * 8]), 16, 0, 0);
    __builtin_amdgcn_global_load_lds((AS1 void*)(aW0 + kt), (AS3 void*)(&Bs[tid * 8]), 16, 0, 0);
    __builtin_amdgcn_global_load_lds((AS1 void*)(aW1 + kt), (AS3 void*)(&Bs[2048 + tid * 8]), 16, 0, 0);
    __syncthreads();
    bf16x8 af[4], bfr[4];
#pragma unroll
    for (int m = 0; m < 4; ++m)
      af[m] = *reinterpret_cast<const bf16x8*>(&As[(wm * 64 + m * 16 + l16) * 32 + g4 * 8]);
#pragma unroll
    for (int n = 0; n < 4; ++n)
      bfr[n] = *reinterpret_cast<const bf16x8*>(&Bs[(wn * 64 + n * 16 + l16) * 32 + g4 * 8]);
#pragma unroll
    for (int m = 0; m < 4; ++m)
#pragma unroll
      for (int n = 0; n < 4; ++n)
        acc[m][n] = __builtin_amdgcn_mfma_f32_16x16x32_bf16(af[m], bfr[n], acc[m][n], 0, 0, 0);
    __syncthreads();
  }

  // fused per-head RMSNorm for q (bn<8) and k (8<=bn<16) columns
  if (bn < 16) {
    const float* w = (bn < 8) ? qw : kw;
    float wv[4];
#pragma unroll
    for (int n = 0; n < 4; ++n) wv[n] = w[n * 16 + l16];
#pragma unroll
    for (int m = 0; m < 4; ++m) {
#pragma unroll
      for (int j = 0; j < 4; ++j) {
        float ss = 0.f;
#pragma unroll
        for (int n = 0; n < 4; ++n) ss = fmaf(acc[m][n][j], acc[m][n][j], ss);
        ss += __shfl_xor(ss, 1);
        ss += __shfl_xor(ss, 2);
        ss += __shfl_xor(ss, 4);
        ss += __shfl_xor(ss, 8);
        const float inv = rsqrtf(ss * (1.0f / 64.0f) + 1e-5f);
#pragma unroll
        for (int n = 0; n < 4; ++n) acc[m][n][j] *= inv * wv[n];
      }
    }
  }

#pragma unroll
  for (int m = 0; m < 4; ++m)
#pragma unroll
    for (int n = 0; n < 4; ++n)
#pragma unroll
      for (int j = 0; j < 4; ++j) {
        long row = bm * 128 + wm * 64 + m * 16 + g4 * 4 + j;
        long col = bn * 128 + wn * 64 + n * 16 + l16;
        C[row * N + col] = f2bf(acc[m][n][j]);
      }
}

// ---------------- FC GEMM: 128x64 tile, fp32 out ----------------
__global__ __launch_bounds__(256, 2) void gemm_fc(const u16* __restrict__ A,
                                                  const u16* __restrict__ W,
                                                  float* __restrict__ C) {
  constexpr int N = 1024, K = 1024;
  __shared__ __align__(16) u16 As[128 * 32];
  __shared__ __align__(16) u16 Bs[64 * 32];
  const int tid = threadIdx.x;
  const int lane = tid & 63;
  const int wid = tid >> 6;
  const int wm = wid >> 1, wn = wid & 1;
  const int l16 = lane & 15, g4 = lane >> 4;
  const long bm = blockIdx.x, bn = blockIdx.y;

  const int srow = tid >> 2;
  const int scol = (tid & 3) * 8;
  const u16* aA0 = A + (bm * 128 + srow) * (long)K + scol;
  const u16* aA1 = aA0 + 64 * (long)K;
  const u16* aW0 = W + (bn * 64 + srow) * (long)K + scol;

  f32x4 acc[4][2] = {};

  for (int kt = 0; kt < K; kt += 32) {
    __builtin_amdgcn_global_load_lds((AS1 void*)(aA0 + kt), (AS3 void*)(&As[tid * 8]), 16, 0, 0);
    __builtin_amdgcn_global_load_lds((AS1 void*)(aA1 + kt), (AS3 void*)(&As[2048 + tid * 8]), 16, 0, 0);
    __builtin_amdgcn_global_load_lds((AS1 void*)(aW0 + kt), (AS3 void*)(&Bs[tid * 8]), 16, 0, 0);
    __syncthreads();
    bf16x8 af[4], bfr[2];
#pragma unroll
    for (int m = 0; m < 4; ++m)
      af[m] = *reinterpret_cast<const bf16x8*>(&As[(wm * 64 + m * 16 + l16) * 32 + g4 * 8]);
#pragma unroll
    for (int n = 0; n < 2; ++n)
      bfr[n] = *reinterpret_cast<const bf16x8*>(&Bs[(wn * 32 + n * 16 + l16) * 32 + g4 * 8]);
#pragma unroll
    for (int m = 0; m < 4; ++m)
#pragma unroll
      for (int n = 0; n < 2; ++n)
        acc[m][n] = __builtin_amdgcn_mfma_f32_16x16x32_bf16(af[m], bfr[n], acc[m][n], 0, 0, 0);
    __syncthreads();
  }

#pragma unroll
  for (int m = 0; m < 4; ++m)
#pragma unroll
    for (int n = 0; n < 2; ++n)
#pragma unroll
      for (int j = 0; j < 4; ++j) {
        long row = bm * 128 + wm * 64 + m * 16 + g4 * 4 + j;
        long col = bn * 64 + wn * 32 + n * 16 + l16;
        C[row * N + col] = acc[m][n][j];
      }
}

// -------- V transpose: qkv v-part -> vt[bh][d=64][key=2048] (both sides coalesced) ----
__global__ __launch_bounds__(256) void vtrans(const u16* __restrict__ qkv,
                                              u16* __restrict__ vt) {
  __shared__ u16 T[64][66];
  const int tid = threadIdx.x;
  const int f = blockIdx.x;  // 1024: xcd = f&7 -> bh = (f&7)*4 + (f>>8)
  const int bh = (f & 7) * 4 + (f >> 8);
  const int ktile = (f >> 3) & 31;
  const long vbase = (long)(bh >> 4) * 2048 * 3072 + (bh & 15) * 64 + 2048;
  const int r = tid >> 2, c = (tid & 3) * 16;
  const u16* src = qkv + vbase + (long)(ktile * 64 + r) * 3072 + c;
  *reinterpret_cast<u16x8*>(&T[r][c]) = *reinterpret_cast<const u16x8*>(src);
  *reinterpret_cast<u16x8*>(&T[r][c + 8]) = *reinterpret_cast<const u16x8*>(src + 8);
  __syncthreads();
  const int dr = tid >> 2, kc = (tid & 3) * 16;
  u16 buf[16];
#pragma unroll
  for (int j = 0; j < 16; ++j) buf[j] = T[kc + j][dr];
  u16* dst = vt + (long)bh * 131072 + (long)dr * 2048 + ktile * 64 + kc;
  *reinterpret_cast<u16x8*>(dst) = *reinterpret_cast<u16x8*>(&buf[0]);
  *reinterpret_cast<u16x8*>(dst + 8) = *reinterpret_cast<u16x8*>(&buf[8]);
}

// ---- causal flash attention: QBLK=64 pairs (i,31-i), 4 waves, XCD-chunked grid -------
// S^T = mfma(K,Q): lane l16 owns q-row; static-max softmax (||q||=||k||=8 => |S|<=8).
// K and V^T staged via global_load_lds with source-side XOR swizzle; V frags hoisted
// (shared by both q-tiles). Zero staging VALU in the loop.
__global__ __launch_bounds__(256, 2) void attn_causal(const u16* __restrict__ qkv,
                                                      const u16* __restrict__ vt,
                                                      u16* __restrict__ o) {
  __shared__ __align__(16) u16 Klds[2][4096];  // [key=64][d=64], swizzled
  __shared__ __align__(16) u16 Vlds[2][4096];  // [d=64][key=64], swizzled
  __shared__ __align__(16) u16 Plds[4][1024];  // per wave [q=16][key=64], swizzled

  const int tid = threadIdx.x, lane = tid & 63, wid = tid >> 6;
  const int l16 = lane & 15, g4 = lane >> 4;
  const int h8 = (l16 & 7) << 4;

  const int f = blockIdx.x;  // 512: xcd = f&7, bh = xcd*4 + (g>>4), i = g&15
  const int g = f >> 3;
  const int bh = (f & 7) * 4 + (g >> 4);
  const int i = g & 15;
  const int iA = i, iB = 31 - i;

  const long base = (long)(bh >> 4) * 2048 * 3072 + (bh & 15) * 64;
  const u16* qb = qkv + base;
  const u16* kb = qkv + base + 1024;
  const u16* vtb = vt + (long)bh * 131072;

  const u16* qpA = qb + ((long)iA * 64 + wid * 16 + l16) * 3072;
  const u16* qpB = qb + ((long)iB * 64 + wid * 16 + l16) * 3072;
  const bf16x8 qA0 = *reinterpret_cast<const bf16x8*>(qpA + g4 * 8);
  const bf16x8 qA1 = *reinterpret_cast<const bf16x8*>(qpA + 32 + g4 * 8);
  const bf16x8 qB0 = *reinterpret_cast<const bf16x8*>(qpB + g4 * 8);
  const bf16x8 qB1 = *reinterpret_cast<const bf16x8*>(qpB + 32 + g4 * 8);

  f32x4 accA[4] = {}, accB[4] = {};
  f32x4 laccA = {}, laccB = {};
  const float cl = 0.125f * 1.4426950408889634f;  // scale * log2(e)
  const float mc = -8.0f * cl;                    // static max = 8

  const int krow = tid >> 3;                                      // 0..31
  const int scolE = (((tid & 7) * 16) ^ ((krow & 7) << 4)) >> 1;  // swizzled col (elems)

  auto stage_issue = [&](int buf, int kt) {
    // K tile [64 keys][64 d]
    __builtin_amdgcn_global_load_lds((AS1 void*)(kb + (long)(kt * 64 + krow) * 3072 + scolE),
                                     (AS3 void*)(&Klds[buf][tid * 8]), 16, 0, 0);
    __builtin_amdgcn_global_load_lds((AS1 void*)(kb + (long)(kt * 64 + krow + 32) * 3072 + scolE),
                                     (AS3 void*)(&Klds[buf][2048 + tid * 8]), 16, 0, 0);
    // V^T tile [64 d][64 keys]
    __builtin_amdgcn_global_load_lds((AS1 void*)(vtb + (long)krow * 2048 + kt * 64 + scolE),
                                     (AS3 void*)(&Vlds[buf][tid * 8]), 16, 0, 0);
    __builtin_amdgcn_global_load_lds((AS1 void*)(vtb + (long)(krow + 32) * 2048 + kt * 64 + scolE),
                                     (AS3 void*)(&Vlds[buf][2048 + tid * 8]), 16, 0, 0);
  };

  auto tile_step = [&](f32x4* acc, f32x4& lacc, const bf16x8& q0, const bf16x8& q1, bool diag,
                       bf16x8 (&kf)[4][2], bf16x8 (&vf)[4][2]) {
    f32x4 s[4];
    __builtin_amdgcn_s_setprio(1);
#pragma unroll
    for (int kn = 0; kn < 4; ++kn) {
      f32x4 z = {0.f, 0.f, 0.f, 0.f};
      z = __builtin_amdgcn_mfma_f32_16x16x32_bf16(kf[kn][0], q0, z, 0, 0, 0);
      z = __builtin_amdgcn_mfma_f32_16x16x32_bf16(kf[kn][1], q1, z, 0, 0, 0);
      s[kn] = z;
    }
    __builtin_amdgcn_s_setprio(0);
    if (diag) {
      const int qrel = wid * 16 + l16;
#pragma unroll
      for (int kn = 0; kn < 4; ++kn)
#pragma unroll
        for (int j = 0; j < 4; ++j)
          if (kn * 16 + g4 * 4 + j > qrel) s[kn][j] = -3e38f;
    }
#pragma unroll
    for (int kn = 0; kn < 4; ++kn) {
#pragma unroll
      for (int j = 0; j < 4; ++j) s[kn][j] = exp2f(fmaf(s[kn][j], cl, mc));
      lacc += s[kn];
    }
    u16* pl = &Plds[wid][0];
#pragma unroll
    for (int kn = 0; kn < 4; ++kn) {
      bf16x4 w4;
      w4[0] = (__bf16)s[kn][0];
      w4[1] = (__bf16)s[kn][1];
      w4[2] = (__bf16)s[kn][2];
      w4[3] = (__bf16)s[kn][3];
      const int boff = (kn * 32 + g4 * 8) ^ h8;
      *reinterpret_cast<bf16x4*>(&pl[l16 * 64 + (boff >> 1)]) = w4;
    }
    const bf16x8 pa0 = *reinterpret_cast<const bf16x8*>(&pl[l16 * 64 + (((g4 * 16) ^ h8) >> 1)]);
    const bf16x8 pa1 =
        *reinterpret_cast<const bf16x8*>(&pl[l16 * 64 + (((64 + g4 * 16) ^ h8) >> 1)]);
    __builtin_amdgcn_s_setprio(1);
#pragma unroll
    for (int n = 0; n < 4; ++n) {
      acc[n] = __builtin_amdgcn_mfma_f32_16x16x32_bf16(pa0, vf[n][0], acc[n], 0, 0, 0);
      acc[n] = __builtin_amdgcn_mfma_f32_16x16x32_bf16(pa1, vf[n][1], acc[n], 0, 0, 0);
    }
    __builtin_amdgcn_s_setprio(0);
  };

  stage_issue(0, 0);
  __syncthreads();

  for (int kt = 0; kt <= iB; ++kt) {
    const int cur = kt & 1, nxt = cur ^ 1;
    if (kt < iB) stage_issue(nxt, kt + 1);

    bf16x8 kf[4][2], vf[4][2];
#pragma unroll
    for (int kn = 0; kn < 4; ++kn) {
      const int row = kn * 16 + l16;
#pragma unroll
      for (int ck = 0; ck < 2; ++ck) {
        const int boff = (ck * 64 + g4 * 16) ^ h8;
        kf[kn][ck] = *reinterpret_cast<const bf16x8*>(&Klds[cur][row * 64 + (boff >> 1)]);
        vf[kn][ck] = *reinterpret_cast<const bf16x8*>(&Vlds[cur][row * 64 + (boff >> 1)]);
      }
    }

    if (kt <= iA) tile_step(accA, laccA, qA0, qA1, kt == iA, kf, vf);
    tile_step(accB, laccB, qB0, qB1, kt == iB, kf, vf);

    __syncthreads();
  }

  // epilogue
  const long obase = (long)(bh >> 4) * 2048 * 1024 + (bh & 15) * 64;
  auto epi = [&](f32x4* acc, const f32x4& lacc, int qt) {
    float l = lacc[0] + lacc[1] + lacc[2] + lacc[3];
    l += __shfl_xor(l, 16);
    l += __shfl_xor(l, 32);
    float lR[4];
#pragma unroll
    for (int j = 0; j < 4; ++j) lR[j] = __shfl(l, g4 * 4 + j, 16);
    u16* op = o + obase + ((long)qt * 64 + wid * 16 + g4 * 4) * 1024;
#pragma unroll
    for (int n = 0; n < 4; ++n)
#pragma unroll
      for (int j = 0; j < 4; ++j)
        op[j * 1024 + n * 16 + l16] = f2bf(acc[n][j] / lR[j]);
  };
  epi(accA, laccA, iA);
  epi(accB, laccB, iB);
}

extern "C" void kernel_launch(void* const* d_in, const int* in_sizes, int n_in,
                              void* d_out, int out_size, void* d_ws, size_t ws_size,
                              hipStream_t stream) {
  const float* x = (const float*)d_in[0];
  // d_in[1] = mask (causal tril -- not needed)
  const float* w_qkv = (const float*)d_in[2];
  const float* w_fc = (const float*)d_in[3];
  const float* qw = (const float*)d_in[4];
  const float* kw = (const float*)d_in[5];
  // d_in[6] = subset_attention_size: with a causal mask the split is an identity.
  float* out = (float*)d_out;

  char* ws = (char*)d_ws;
  u16* xb    = (u16*)(ws);                   // 8 MB (reused as vt after gemm_qkv)
  u16* wqkvb = (u16*)(ws + (8L << 20));      // 6 MB
  u16* wfcb  = (u16*)(ws + (14L << 20));     // 2 MB
  u16* qkv   = (u16*)(ws + (16L << 20));     // 24 MB
  u16* ob    = (u16*)(ws + (40L << 20));     // 8 MB
  u16* vt    = xb;                           // xb is dead after gemm_qkv

  cvt_all<<<8192, 256, 0, stream>>>(x, w_qkv, w_fc, xb, wqkvb, wfcb);
  gemm_qkv<<<dim3(32, 24), 256, 0, stream>>>(xb, wqkvb, qkv, qw, kw);
  vtrans<<<1024, 256, 0, stream>>>(qkv, vt);
  attn_causal<<<512, 256, 0, stream>>>(qkv, vt, ob);
  gemm_fc<<<dim3(32, 16), 256, 0, stream>>>(ob, wfcb, out);
}

// Round 6
// 113.059 us; speedup vs baseline: 1.8505x; 1.0037x over previous
//
#include <hip/hip_runtime.h>

typedef __bf16 bf16x8 __attribute__((ext_vector_type(8)));
typedef __bf16 bf16x4 __attribute__((ext_vector_type(4)));
typedef float f32x4 __attribute__((ext_vector_type(4)));
typedef unsigned short u16;
typedef unsigned int u32;
typedef unsigned short u16x4 __attribute__((ext_vector_type(4)));
typedef unsigned short u16x8 __attribute__((ext_vector_type(8)));

#define AS1 __attribute__((address_space(1)))
#define AS3 __attribute__((address_space(3)))

__device__ __forceinline__ u16 f2bf(float f) {
  unsigned u = __builtin_bit_cast(unsigned, f);
  u += 0x7fffu + ((u >> 16) & 1u);
  return (u16)(u >> 16);
}

// ---------------- fp32 -> bf16 convert (x, w_qkv, w_fc fused) ----------------
__global__ __launch_bounds__(256) void cvt_all(const float* __restrict__ x,
                                               const float* __restrict__ wq,
                                               const float* __restrict__ wf,
                                               u16* __restrict__ xb, u16* __restrict__ wqb,
                                               u16* __restrict__ wfb) {
  long i = ((long)blockIdx.x * 256 + threadIdx.x) * 4;
  const float* src;
  u16* dst;
  long off;
  if (i < 4194304L) {
    src = x; dst = xb; off = i;
  } else if (i < 7340032L) {
    src = wq; dst = wqb; off = i - 4194304L;
  } else {
    src = wf; dst = wfb; off = i - 7340032L;
  }
  float4 v = *reinterpret_cast<const float4*>(src + off);
  u16x4 o;
  o.x = f2bf(v.x); o.y = f2bf(v.y); o.z = f2bf(v.z); o.w = f2bf(v.w);
  *reinterpret_cast<u16x4*>(dst + off) = o;
}

// -------- QKV GEMM: C[4096][3072] = X[4096][1024] * W[3072][1024]^T, RMS fused -------
// q-heads additionally pre-scaled by 0.125*log2(e) so attention S is in exp2 domain.
__global__ __launch_bounds__(256, 2) void gemm_qkv(const u16* __restrict__ A,
                                                   const u16* __restrict__ W,
                                                   u16* __restrict__ C,
                                                   const float* __restrict__ qw,
                                                   const float* __restrict__ kw) {
  constexpr int N = 3072, K = 1024;
  __shared__ __align__(16) u16 As[128 * 32];
  __shared__ __align__(16) u16 Bs[128 * 32];
  const int tid = threadIdx.x;
  const int lane = tid & 63;
  const int wid = tid >> 6;
  const int wm = wid >> 1, wn = wid & 1;
  const int l16 = lane & 15, g4 = lane >> 4;
  const long bm = blockIdx.x, bn = blockIdx.y;

  const int srow = tid >> 2;
  const int scol = (tid & 3) * 8;
  const u16* aA0 = A + (bm * 128 + srow) * (long)K + scol;
  const u16* aA1 = aA0 + 64 * (long)K;
  const u16* aW0 = W + (bn * 128 + srow) * (long)K + scol;
  const u16* aW1 = aW0 + 64 * (long)K;

  f32x4 acc[4][4] = {};

  for (int kt = 0; kt < K; kt += 32) {
    __builtin_amdgcn_global_load_lds((AS1 void*)(aA0 + kt), (AS3 void*)(&As[tid * 8]), 16, 0, 0);
    __builtin_amdgcn_global_load_lds((AS1 void*)(aA1 + kt), (AS3 void*)(&As[2048 + tid * 8]), 16, 0, 0);
    __builtin_amdgcn_global_load_lds((AS1 void*)(aW0 + kt), (AS3 void*)(&Bs[tid * 8]), 16, 0, 0);
    __builtin_amdgcn_global_load_lds((AS1 void*)(aW1 + kt), (AS3 void*)(&Bs[2048 + tid * 8]), 16, 0, 0);
    __syncthreads();
    bf16x8 af[4], bfr[4];
#pragma unroll
    for (int m = 0; m < 4; ++m)
      af[m] = *reinterpret_cast<const bf16x8*>(&As[(wm * 64 + m * 16 + l16) * 32 + g4 * 8]);
#pragma unroll
    for (int n = 0; n < 4; ++n)
      bfr[n] = *reinterpret_cast<const bf16x8*>(&Bs[(wn * 64 + n * 16 + l16) * 32 + g4 * 8]);
#pragma unroll
    for (int m = 0; m < 4; ++m)
#pragma unroll
      for (int n = 0; n < 4; ++n)
        acc[m][n] = __builtin_amdgcn_mfma_f32_16x16x32_bf16(af[m], bfr[n], acc[m][n], 0, 0, 0);
    __syncthreads();
  }

  // fused per-head RMSNorm for q (bn<8, with attn scale folded in) and k (8<=bn<16)
  if (bn < 16) {
    const float qscale = 0.18033688011112042f;  // 0.125 * log2(e)
    const float* w = (bn < 8) ? qw : kw;
    const float ws = (bn < 8) ? qscale : 1.0f;
    float wv[4];
#pragma unroll
    for (int n = 0; n < 4; ++n) wv[n] = w[n * 16 + l16] * ws;
#pragma unroll
    for (int m = 0; m < 4; ++m) {
#pragma unroll
      for (int j = 0; j < 4; ++j) {
        float ss = 0.f;
#pragma unroll
        for (int n = 0; n < 4; ++n) ss = fmaf(acc[m][n][j], acc[m][n][j], ss);
        ss += __shfl_xor(ss, 1);
        ss += __shfl_xor(ss, 2);
        ss += __shfl_xor(ss, 4);
        ss += __shfl_xor(ss, 8);
        const float inv = rsqrtf(ss * (1.0f / 64.0f) + 1e-5f);
#pragma unroll
        for (int n = 0; n < 4; ++n) acc[m][n][j] *= inv * wv[n];
      }
    }
  }

#pragma unroll
  for (int m = 0; m < 4; ++m)
#pragma unroll
    for (int n = 0; n < 4; ++n)
#pragma unroll
      for (int j = 0; j < 4; ++j) {
        long row = bm * 128 + wm * 64 + m * 16 + g4 * 4 + j;
        long col = bn * 128 + wn * 64 + n * 16 + l16;
        C[row * N + col] = f2bf(acc[m][n][j]);
      }
}

// ---------------- FC GEMM: 128x64 tile, fp32 out ----------------
__global__ __launch_bounds__(256, 2) void gemm_fc(const u16* __restrict__ A,
                                                  const u16* __restrict__ W,
                                                  float* __restrict__ C) {
  constexpr int N = 1024, K = 1024;
  __shared__ __align__(16) u16 As[128 * 32];
  __shared__ __align__(16) u16 Bs[64 * 32];
  const int tid = threadIdx.x;
  const int lane = tid & 63;
  const int wid = tid >> 6;
  const int wm = wid >> 1, wn = wid & 1;
  const int l16 = lane & 15, g4 = lane >> 4;
  const long bm = blockIdx.x, bn = blockIdx.y;

  const int srow = tid >> 2;
  const int scol = (tid & 3) * 8;
  const u16* aA0 = A + (bm * 128 + srow) * (long)K + scol;
  const u16* aA1 = aA0 + 64 * (long)K;
  const u16* aW0 = W + (bn * 64 + srow) * (long)K + scol;

  f32x4 acc[4][2] = {};

  for (int kt = 0; kt < K; kt += 32) {
    __builtin_amdgcn_global_load_lds((AS1 void*)(aA0 + kt), (AS3 void*)(&As[tid * 8]), 16, 0, 0);
    __builtin_amdgcn_global_load_lds((AS1 void*)(aA1 + kt), (AS3 void*)(&As[2048 + tid * 8]), 16, 0, 0);
    __builtin_amdgcn_global_load_lds((AS1 void*)(aW0 + kt), (AS3 void*)(&Bs[tid * 8]), 16, 0, 0);
    __syncthreads();
    bf16x8 af[4], bfr[2];
#pragma unroll
    for (int m = 0; m < 4; ++m)
      af[m] = *reinterpret_cast<const bf16x8*>(&As[(wm * 64 + m * 16 + l16) * 32 + g4 * 8]);
#pragma unroll
    for (int n = 0; n < 2; ++n)
      bfr[n] = *reinterpret_cast<const bf16x8*>(&Bs[(wn * 32 + n * 16 + l16) * 32 + g4 * 8]);
#pragma unroll
    for (int m = 0; m < 4; ++m)
#pragma unroll
      for (int n = 0; n < 2; ++n)
        acc[m][n] = __builtin_amdgcn_mfma_f32_16x16x32_bf16(af[m], bfr[n], acc[m][n], 0, 0, 0);
    __syncthreads();
  }

#pragma unroll
  for (int m = 0; m < 4; ++m)
#pragma unroll
    for (int n = 0; n < 2; ++n)
#pragma unroll
      for (int j = 0; j < 4; ++j) {
        long row = bm * 128 + wm * 64 + m * 16 + g4 * 4 + j;
        long col = bn * 64 + wn * 32 + n * 16 + l16;
        C[row * N + col] = acc[m][n][j];
      }
}

// -------- V transpose: qkv v-part -> vt[bh][d=64][key=2048] (both sides coalesced) ----
__global__ __launch_bounds__(256) void vtrans(const u16* __restrict__ qkv,
                                              u16* __restrict__ vt) {
  __shared__ u16 T[64][66];
  const int tid = threadIdx.x;
  const int f = blockIdx.x;  // 1024: xcd = f&7 -> bh = (f&7)*4 + (f>>8)
  const int bh = (f & 7) * 4 + (f >> 8);
  const int ktile = (f >> 3) & 31;
  const long vbase = (long)(bh >> 4) * 2048 * 3072 + (bh & 15) * 64 + 2048;
  const int r = tid >> 2, c = (tid & 3) * 16;
  const u16* src = qkv + vbase + (long)(ktile * 64 + r) * 3072 + c;
  *reinterpret_cast<u16x8*>(&T[r][c]) = *reinterpret_cast<const u16x8*>(src);
  *reinterpret_cast<u16x8*>(&T[r][c + 8]) = *reinterpret_cast<const u16x8*>(src + 8);
  __syncthreads();
  const int dr = tid >> 2, kc = (tid & 3) * 16;
  u16 buf[16];
#pragma unroll
  for (int j = 0; j < 16; ++j) buf[j] = T[kc + j][dr];
  u16* dst = vt + (long)bh * 131072 + (long)dr * 2048 + ktile * 64 + kc;
  *reinterpret_cast<u16x8*>(dst) = *reinterpret_cast<u16x8*>(&buf[0]);
  *reinterpret_cast<u16x8*>(dst + 8) = *reinterpret_cast<u16x8*>(&buf[8]);
}

// ---- causal flash attention: QBLK=64 pairs (i,31-i), KVBLK=128 staging ---------------
// q pre-scaled by 0.125*log2e in gemm_qkv; static-max shift cancels => P' = exp2(s),
// l' = rowsum(P') accumulated via MFMA with an all-ones B fragment (no VALU adds).
// One barrier per 128 keys. K and V^T staged via global_load_lds, source XOR-swizzled.
__global__ __launch_bounds__(256, 2) void attn_causal(const u16* __restrict__ qkv,
                                                      const u16* __restrict__ vt,
                                                      u16* __restrict__ o) {
  __shared__ __align__(16) u16 Klds[2][8192];  // [key=128][d=64], swizzled
  __shared__ __align__(16) u16 Vlds[2][8192];  // [d=64][key=128], swizzled
  __shared__ __align__(16) u16 Plds[4][1024];  // per wave [q=16][key=64], swizzled

  const int tid = threadIdx.x, lane = tid & 63, wid = tid >> 6;
  const int l16 = lane & 15, g4 = lane >> 4;
  const int h8 = (l16 & 7) << 4;

  const int f = blockIdx.x;  // 512: xcd = f&7, bh = xcd*4 + (g>>4), i = g&15
  const int g = f >> 3;
  const int bh = (f & 7) * 4 + (g >> 4);
  const int i = g & 15;
  const int iA = i, iB = 31 - i;  // 64-row q-tile indices

  const long base = (long)(bh >> 4) * 2048 * 3072 + (bh & 15) * 64;
  const u16* qb = qkv + base;
  const u16* kb = qkv + base + 1024;
  const u16* vtb = vt + (long)bh * 131072;

  const u16* qpA = qb + ((long)iA * 64 + wid * 16 + l16) * 3072;
  const u16* qpB = qb + ((long)iB * 64 + wid * 16 + l16) * 3072;
  const bf16x8 qA0 = *reinterpret_cast<const bf16x8*>(qpA + g4 * 8);
  const bf16x8 qA1 = *reinterpret_cast<const bf16x8*>(qpA + 32 + g4 * 8);
  const bf16x8 qB0 = *reinterpret_cast<const bf16x8*>(qpB + g4 * 8);
  const bf16x8 qB1 = *reinterpret_cast<const bf16x8*>(qpB + 32 + g4 * 8);

  f32x4 accA[4] = {}, accB[4] = {};
  f32x4 laccA = {}, laccB = {};

  bf16x8 ones;
#pragma unroll
  for (int j = 0; j < 8; ++j) ones[j] = (__bf16)1.0f;

  // staging addresses (row & 7 invariant under +16/+32 row steps)
  const int krow = tid >> 3;                                      // 0..31
  const int scolE = (((tid & 7) * 16) ^ ((krow & 7) << 4)) >> 1;  // K swizzled col (elems)
  const int vrow = tid >> 4;                                      // 0..15
  const int vcolE = (((tid & 15) * 16) ^ ((vrow & 7) << 4)) >> 1; // V swizzled col (elems)

  auto stage_issue = [&](int buf, int kt) {
    // K tile [128 keys][64 d] from qkv
    const u16* ks = kb + (long)(kt * 128 + krow) * 3072 + scolE;
#pragma unroll
    for (int c = 0; c < 4; ++c)
      __builtin_amdgcn_global_load_lds((AS1 void*)(ks + (long)(32 * c) * 3072),
                                       (AS3 void*)(&Klds[buf][c * 2048 + tid * 8]), 16, 0, 0);
    // V^T tile [64 d][128 keys] from vt
    const u16* vs = vtb + (long)vrow * 2048 + kt * 128 + vcolE;
#pragma unroll
    for (int c = 0; c < 4; ++c)
      __builtin_amdgcn_global_load_lds((AS1 void*)(vs + (long)(16 * c) * 2048),
                                       (AS3 void*)(&Vlds[buf][c * 2048 + tid * 8]), 16, 0, 0);
  };

  auto tile_step = [&](f32x4* acc, f32x4& lacc, const bf16x8& q0, const bf16x8& q1, bool diag,
                       bf16x8 (&kf)[4][2], bf16x8 (&vf)[4][2]) {
    f32x4 s[4];
    __builtin_amdgcn_s_setprio(1);
#pragma unroll
    for (int kn = 0; kn < 4; ++kn) {
      f32x4 z = {0.f, 0.f, 0.f, 0.f};
      z = __builtin_amdgcn_mfma_f32_16x16x32_bf16(kf[kn][0], q0, z, 0, 0, 0);
      z = __builtin_amdgcn_mfma_f32_16x16x32_bf16(kf[kn][1], q1, z, 0, 0, 0);
      s[kn] = z;
    }
    __builtin_amdgcn_s_setprio(0);
    if (diag) {
      const int qrel = wid * 16 + l16;
#pragma unroll
      for (int kn = 0; kn < 4; ++kn)
#pragma unroll
        for (int j = 0; j < 4; ++j)
          if (kn * 16 + g4 * 4 + j > qrel) s[kn][j] = -3e38f;
    }
#pragma unroll
    for (int kn = 0; kn < 4; ++kn)
#pragma unroll
      for (int j = 0; j < 4; ++j) s[kn][j] = exp2f(s[kn][j]);
    u16* pl = &Plds[wid][0];
#pragma unroll
    for (int kn = 0; kn < 4; ++kn) {
      bf16x4 w4;
      w4[0] = (__bf16)s[kn][0];
      w4[1] = (__bf16)s[kn][1];
      w4[2] = (__bf16)s[kn][2];
      w4[3] = (__bf16)s[kn][3];
      const int boff = (kn * 32 + g4 * 8) ^ h8;
      *reinterpret_cast<bf16x4*>(&pl[l16 * 64 + (boff >> 1)]) = w4;
    }
    const bf16x8 pa0 = *reinterpret_cast<const bf16x8*>(&pl[l16 * 64 + (((g4 * 16) ^ h8) >> 1)]);
    const bf16x8 pa1 =
        *reinterpret_cast<const bf16x8*>(&pl[l16 * 64 + (((64 + g4 * 16) ^ h8) >> 1)]);
    __builtin_amdgcn_s_setprio(1);
    lacc = __builtin_amdgcn_mfma_f32_16x16x32_bf16(pa0, ones, lacc, 0, 0, 0);
    lacc = __builtin_amdgcn_mfma_f32_16x16x32_bf16(pa1, ones, lacc, 0, 0, 0);
#pragma unroll
    for (int n = 0; n < 4; ++n) {
      acc[n] = __builtin_amdgcn_mfma_f32_16x16x32_bf16(pa0, vf[n][0], acc[n], 0, 0, 0);
      acc[n] = __builtin_amdgcn_mfma_f32_16x16x32_bf16(pa1, vf[n][1], acc[n], 0, 0, 0);
    }
    __builtin_amdgcn_s_setprio(0);
  };

  stage_issue(0, 0);
  __syncthreads();

  const int ktmax = (iB + 2) >> 1;  // 128-key stages
  for (int kt = 0; kt < ktmax; ++kt) {
    const int cur = kt & 1, nxt = cur ^ 1;
    if (kt + 1 < ktmax) stage_issue(nxt, kt + 1);

#pragma unroll
    for (int sub = 0; sub < 2; ++sub) {
      const int kt2 = kt * 2 + sub;
      if (kt2 > iB) break;

      bf16x8 kf[4][2], vf[4][2];
#pragma unroll
      for (int kn = 0; kn < 4; ++kn) {
        const int krowf = sub * 64 + kn * 16 + l16;   // key row in Klds
        const int vrowf = kn * 16 + l16;              // d row in Vlds
#pragma unroll
        for (int ck = 0; ck < 2; ++ck) {
          const int kboff = (ck * 64 + g4 * 16) ^ h8;
          kf[kn][ck] = *reinterpret_cast<const bf16x8*>(&Klds[cur][krowf * 64 + (kboff >> 1)]);
          const int vboff = (sub * 128 + ck * 64 + g4 * 16) ^ h8;
          vf[kn][ck] = *reinterpret_cast<const bf16x8*>(&Vlds[cur][vrowf * 128 + (vboff >> 1)]);
        }
      }

      if (kt2 <= iA) tile_step(accA, laccA, qA0, qA1, kt2 == iA, kf, vf);
      tile_step(accB, laccB, qB0, qB1, kt2 == iB, kf, vf);
    }
    __syncthreads();
  }

  // epilogue: l for row g4*4+j is lacc[j] (all lanes hold it)
  const long obase = (long)(bh >> 4) * 2048 * 1024 + (bh & 15) * 64;
  auto epi = [&](f32x4* acc, const f32x4& lacc, int qt) {
    u16* op = o + obase + ((long)qt * 64 + wid * 16 + g4 * 4) * 1024;
#pragma unroll
    for (int n = 0; n < 4; ++n)
#pragma unroll
      for (int j = 0; j < 4; ++j)
        op[j * 1024 + n * 16 + l16] = f2bf(acc[n][j] / lacc[j]);
  };
  epi(accA, laccA, iA);
  epi(accB, laccB, iB);
}

extern "C" void kernel_launch(void* const* d_in, const int* in_sizes, int n_in,
                              void* d_out, int out_size, void* d_ws, size_t ws_size,
                              hipStream_t stream) {
  const float* x = (const float*)d_in[0];
  // d_in[1] = mask (causal tril -- not needed)
  const float* w_qkv = (const float*)d_in[2];
  const float* w_fc = (const float*)d_in[3];
  const float* qw = (const float*)d_in[4];
  const float* kw = (const float*)d_in[5];
  // d_in[6] = subset_attention_size: with a causal mask the split is an identity.
  float* out = (float*)d_out;

  char* ws = (char*)d_ws;
  u16* xb    = (u16*)(ws);                   // 8 MB (reused as vt after gemm_qkv)
  u16* wqkvb = (u16*)(ws + (8L << 20));      // 6 MB
  u16* wfcb  = (u16*)(ws + (14L << 20));     // 2 MB
  u16* qkv   = (u16*)(ws + (16L << 20));     // 24 MB
  u16* ob    = (u16*)(ws + (40L << 20));     // 8 MB
  u16* vt    = xb;                           // xb is dead after gemm_qkv

  cvt_all<<<8192, 256, 0, stream>>>(x, w_qkv, w_fc, xb, wqkvb, wfcb);
  gemm_qkv<<<dim3(32, 24), 256, 0, stream>>>(xb, wqkvb, qkv, qw, kw);
  vtrans<<<1024, 256, 0, stream>>>(qkv, vt);
  attn_causal<<<512, 256, 0, stream>>>(qkv, vt, ob);
  gemm_fc<<<dim3(32, 16), 256, 0, stream>>>(ob, wfcb, out);
}

// Round 7
// 111.374 us; speedup vs baseline: 1.8785x; 1.0151x over previous
//
#include <hip/hip_runtime.h>

typedef __bf16 bf16x8 __attribute__((ext_vector_type(8)));
typedef __bf16 bf16x4 __attribute__((ext_vector_type(4)));
typedef float f32x4 __attribute__((ext_vector_type(4)));
typedef unsigned short u16;
typedef unsigned int u32;
typedef unsigned short u16x4 __attribute__((ext_vector_type(4)));
typedef unsigned short u16x8 __attribute__((ext_vector_type(8)));

#define AS1 __attribute__((address_space(1)))
#define AS3 __attribute__((address_space(3)))

__device__ __forceinline__ u16 f2bf(float f) {
  unsigned u = __builtin_bit_cast(unsigned, f);
  u += 0x7fffu + ((u >> 16) & 1u);
  return (u16)(u >> 16);
}

// ---------------- fp32 -> bf16 convert (x, w_qkv, w_fc fused) ----------------
__global__ __launch_bounds__(256) void cvt_all(const float* __restrict__ x,
                                               const float* __restrict__ wq,
                                               const float* __restrict__ wf,
                                               u16* __restrict__ xb, u16* __restrict__ wqb,
                                               u16* __restrict__ wfb) {
  long i = ((long)blockIdx.x * 256 + threadIdx.x) * 4;
  const float* src;
  u16* dst;
  long off;
  if (i < 4194304L) {
    src = x; dst = xb; off = i;
  } else if (i < 7340032L) {
    src = wq; dst = wqb; off = i - 4194304L;
  } else {
    src = wf; dst = wfb; off = i - 7340032L;
  }
  float4 v = *reinterpret_cast<const float4*>(src + off);
  u16x4 o;
  o.x = f2bf(v.x); o.y = f2bf(v.y); o.z = f2bf(v.z); o.w = f2bf(v.w);
  *reinterpret_cast<u16x4*>(dst + off) = o;
}

// -------- QKV GEMM: C[4096][3072] = X[4096][1024] * W[3072][1024]^T, RMS fused -------
// q-heads additionally pre-scaled by 0.125*log2(e) so attention S is in exp2 domain.
__global__ __launch_bounds__(256, 2) void gemm_qkv(const u16* __restrict__ A,
                                                   const u16* __restrict__ W,
                                                   u16* __restrict__ C,
                                                   const float* __restrict__ qw,
                                                   const float* __restrict__ kw) {
  constexpr int N = 3072, K = 1024;
  __shared__ __align__(16) u16 As[128 * 32];
  __shared__ __align__(16) u16 Bs[128 * 32];
  const int tid = threadIdx.x;
  const int lane = tid & 63;
  const int wid = tid >> 6;
  const int wm = wid >> 1, wn = wid & 1;
  const int l16 = lane & 15, g4 = lane >> 4;
  const long bm = blockIdx.x, bn = blockIdx.y;

  const int srow = tid >> 2;
  const int scol = (tid & 3) * 8;
  const u16* aA0 = A + (bm * 128 + srow) * (long)K + scol;
  const u16* aA1 = aA0 + 64 * (long)K;
  const u16* aW0 = W + (bn * 128 + srow) * (long)K + scol;
  const u16* aW1 = aW0 + 64 * (long)K;

  f32x4 acc[4][4] = {};

  for (int kt = 0; kt < K; kt += 32) {
    __builtin_amdgcn_global_load_lds((AS1 void*)(aA0 + kt), (AS3 void*)(&As[tid * 8]), 16, 0, 0);
    __builtin_amdgcn_global_load_lds((AS1 void*)(aA1 + kt), (AS3 void*)(&As[2048 + tid * 8]), 16, 0, 0);
    __builtin_amdgcn_global_load_lds((AS1 void*)(aW0 + kt), (AS3 void*)(&Bs[tid * 8]), 16, 0, 0);
    __builtin_amdgcn_global_load_lds((AS1 void*)(aW1 + kt), (AS3 void*)(&Bs[2048 + tid * 8]), 16, 0, 0);
    __syncthreads();
    bf16x8 af[4], bfr[4];
#pragma unroll
    for (int m = 0; m < 4; ++m)
      af[m] = *reinterpret_cast<const bf16x8*>(&As[(wm * 64 + m * 16 + l16) * 32 + g4 * 8]);
#pragma unroll
    for (int n = 0; n < 4; ++n)
      bfr[n] = *reinterpret_cast<const bf16x8*>(&Bs[(wn * 64 + n * 16 + l16) * 32 + g4 * 8]);
#pragma unroll
    for (int m = 0; m < 4; ++m)
#pragma unroll
      for (int n = 0; n < 4; ++n)
        acc[m][n] = __builtin_amdgcn_mfma_f32_16x16x32_bf16(af[m], bfr[n], acc[m][n], 0, 0, 0);
    __syncthreads();
  }

  // fused per-head RMSNorm for q (bn<8, with attn scale folded in) and k (8<=bn<16)
  if (bn < 16) {
    const float qscale = 0.18033688011112042f;  // 0.125 * log2(e)
    const float* w = (bn < 8) ? qw : kw;
    const float ws = (bn < 8) ? qscale : 1.0f;
    float wv[4];
#pragma unroll
    for (int n = 0; n < 4; ++n) wv[n] = w[n * 16 + l16] * ws;
#pragma unroll
    for (int m = 0; m < 4; ++m) {
#pragma unroll
      for (int j = 0; j < 4; ++j) {
        float ss = 0.f;
#pragma unroll
        for (int n = 0; n < 4; ++n) ss = fmaf(acc[m][n][j], acc[m][n][j], ss);
        ss += __shfl_xor(ss, 1);
        ss += __shfl_xor(ss, 2);
        ss += __shfl_xor(ss, 4);
        ss += __shfl_xor(ss, 8);
        const float inv = rsqrtf(ss * (1.0f / 64.0f) + 1e-5f);
#pragma unroll
        for (int n = 0; n < 4; ++n) acc[m][n][j] *= inv * wv[n];
      }
    }
  }

#pragma unroll
  for (int m = 0; m < 4; ++m)
#pragma unroll
    for (int n = 0; n < 4; ++n)
#pragma unroll
      for (int j = 0; j < 4; ++j) {
        long row = bm * 128 + wm * 64 + m * 16 + g4 * 4 + j;
        long col = bn * 128 + wn * 64 + n * 16 + l16;
        C[row * N + col] = f2bf(acc[m][n][j]);
      }
}

// ---------------- FC GEMM: 128x64 tile, fp32 out ----------------
__global__ __launch_bounds__(256, 2) void gemm_fc(const u16* __restrict__ A,
                                                  const u16* __restrict__ W,
                                                  float* __restrict__ C) {
  constexpr int N = 1024, K = 1024;
  __shared__ __align__(16) u16 As[128 * 32];
  __shared__ __align__(16) u16 Bs[64 * 32];
  const int tid = threadIdx.x;
  const int lane = tid & 63;
  const int wid = tid >> 6;
  const int wm = wid >> 1, wn = wid & 1;
  const int l16 = lane & 15, g4 = lane >> 4;
  const long bm = blockIdx.x, bn = blockIdx.y;

  const int srow = tid >> 2;
  const int scol = (tid & 3) * 8;
  const u16* aA0 = A + (bm * 128 + srow) * (long)K + scol;
  const u16* aA1 = aA0 + 64 * (long)K;
  const u16* aW0 = W + (bn * 64 + srow) * (long)K + scol;

  f32x4 acc[4][2] = {};

  for (int kt = 0; kt < K; kt += 32) {
    __builtin_amdgcn_global_load_lds((AS1 void*)(aA0 + kt), (AS3 void*)(&As[tid * 8]), 16, 0, 0);
    __builtin_amdgcn_global_load_lds((AS1 void*)(aA1 + kt), (AS3 void*)(&As[2048 + tid * 8]), 16, 0, 0);
    __builtin_amdgcn_global_load_lds((AS1 void*)(aW0 + kt), (AS3 void*)(&Bs[tid * 8]), 16, 0, 0);
    __syncthreads();
    bf16x8 af[4], bfr[2];
#pragma unroll
    for (int m = 0; m < 4; ++m)
      af[m] = *reinterpret_cast<const bf16x8*>(&As[(wm * 64 + m * 16 + l16) * 32 + g4 * 8]);
#pragma unroll
    for (int n = 0; n < 2; ++n)
      bfr[n] = *reinterpret_cast<const bf16x8*>(&Bs[(wn * 32 + n * 16 + l16) * 32 + g4 * 8]);
#pragma unroll
    for (int m = 0; m < 4; ++m)
#pragma unroll
      for (int n = 0; n < 2; ++n)
        acc[m][n] = __builtin_amdgcn_mfma_f32_16x16x32_bf16(af[m], bfr[n], acc[m][n], 0, 0, 0);
    __syncthreads();
  }

#pragma unroll
  for (int m = 0; m < 4; ++m)
#pragma unroll
    for (int n = 0; n < 2; ++n)
#pragma unroll
      for (int j = 0; j < 4; ++j) {
        long row = bm * 128 + wm * 64 + m * 16 + g4 * 4 + j;
        long col = bn * 64 + wn * 32 + n * 16 + l16;
        C[row * N + col] = acc[m][n][j];
      }
}

// -------- V transpose: qkv v-part -> vt[bh][d=64][key=2048] (both sides coalesced) ----
__global__ __launch_bounds__(256) void vtrans(const u16* __restrict__ qkv,
                                              u16* __restrict__ vt) {
  __shared__ u16 T[64][66];
  const int tid = threadIdx.x;
  const int f = blockIdx.x;  // 1024: xcd = f&7 -> bh = (f&7)*4 + (f>>8)
  const int bh = (f & 7) * 4 + (f >> 8);
  const int ktile = (f >> 3) & 31;
  const long vbase = (long)(bh >> 4) * 2048 * 3072 + (bh & 15) * 64 + 2048;
  const int r = tid >> 2, c = (tid & 3) * 16;
  const u16* src = qkv + vbase + (long)(ktile * 64 + r) * 3072 + c;
  *reinterpret_cast<u16x8*>(&T[r][c]) = *reinterpret_cast<const u16x8*>(src);
  *reinterpret_cast<u16x8*>(&T[r][c + 8]) = *reinterpret_cast<const u16x8*>(src + 8);
  __syncthreads();
  const int dr = tid >> 2, kc = (tid & 3) * 16;
  u16 buf[16];
#pragma unroll
  for (int j = 0; j < 16; ++j) buf[j] = T[kc + j][dr];
  u16* dst = vt + (long)bh * 131072 + (long)dr * 2048 + ktile * 64 + kc;
  *reinterpret_cast<u16x8*>(dst) = *reinterpret_cast<u16x8*>(&buf[0]);
  *reinterpret_cast<u16x8*>(dst + 8) = *reinterpret_cast<u16x8*>(&buf[8]);
}

// ---- causal flash attention: one 64-row q-tile per block, 4 blocks/CU ---------------
// grid 1024: xcd = f&7, per-XCD g = f>>3 -> bh = xcd*4 + (g>>5), tile via balanced perm.
// Anti-correlated tile assignment: zig-zag on w&1 and reflection on hb&1 so any CU's 4
// resident blocks sum to ~66 iterations under either consecutive-g or stride-32-g
// assignment. Static-max softmax in exp2 domain; l via MFMA-ones; K/V^T via
// global_load_lds source-swizzled; K-frags and V-frags time-disjoint (register reuse).
__global__ __launch_bounds__(256, 4) void attn_causal(const u16* __restrict__ qkv,
                                                      const u16* __restrict__ vt,
                                                      u16* __restrict__ o) {
  __shared__ __align__(16) u16 Klds[2][4096];  // [key=64][d=64], swizzled
  __shared__ __align__(16) u16 Vlds[2][4096];  // [d=64][key=64], swizzled
  __shared__ __align__(16) u16 Plds[4][1024];  // per wave [q=16][key=64], swizzled

  const int tid = threadIdx.x, lane = tid & 63, wid = tid >> 6;
  const int l16 = lane & 15, g4 = lane >> 4;
  const int h8 = (l16 & 7) << 4;

  const int f = blockIdx.x;
  const int xcd = f & 7;
  const int g = f >> 3;           // 0..127 per XCD
  const int hb = g >> 5;          // 0..3 -> head within XCD
  const int w = g & 31;           // 0..31 -> tile permutation input
  const int bh = xcd * 4 + hb;
  const int basei = (w & 1) ? (31 - (w >> 1)) : (w >> 1);
  const int it = (hb & 1) ? (31 - basei) : basei;  // q-tile index 0..31

  const long base = (long)(bh >> 4) * 2048 * 3072 + (bh & 15) * 64;
  const u16* qb = qkv + base;
  const u16* kb = qkv + base + 1024;
  const u16* vtb = vt + (long)bh * 131072;

  const u16* qp = qb + ((long)it * 64 + wid * 16 + l16) * 3072;
  const bf16x8 q0 = *reinterpret_cast<const bf16x8*>(qp + g4 * 8);
  const bf16x8 q1 = *reinterpret_cast<const bf16x8*>(qp + 32 + g4 * 8);

  f32x4 acc[4] = {};
  f32x4 lacc = {};

  bf16x8 ones;
#pragma unroll
  for (int j = 0; j < 8; ++j) ones[j] = (__bf16)1.0f;

  const int krow = tid >> 3;                                      // 0..31
  const int scolE = (((tid & 7) * 16) ^ ((krow & 7) << 4)) >> 1;  // swizzled col (elems)

  auto stage_issue = [&](int buf, int kt) {
    __builtin_amdgcn_global_load_lds((AS1 void*)(kb + (long)(kt * 64 + krow) * 3072 + scolE),
                                     (AS3 void*)(&Klds[buf][tid * 8]), 16, 0, 0);
    __builtin_amdgcn_global_load_lds((AS1 void*)(kb + (long)(kt * 64 + krow + 32) * 3072 + scolE),
                                     (AS3 void*)(&Klds[buf][2048 + tid * 8]), 16, 0, 0);
    __builtin_amdgcn_global_load_lds((AS1 void*)(vtb + (long)krow * 2048 + kt * 64 + scolE),
                                     (AS3 void*)(&Vlds[buf][tid * 8]), 16, 0, 0);
    __builtin_amdgcn_global_load_lds((AS1 void*)(vtb + (long)(krow + 32) * 2048 + kt * 64 + scolE),
                                     (AS3 void*)(&Vlds[buf][2048 + tid * 8]), 16, 0, 0);
  };

  auto tile_step = [&](int cur, bool diag) {
    // K fragments (time-disjoint from V fragments -> register reuse)
    bf16x8 kf[4][2];
#pragma unroll
    for (int kn = 0; kn < 4; ++kn) {
      const int row = kn * 16 + l16;
#pragma unroll
      for (int ck = 0; ck < 2; ++ck)
        kf[kn][ck] = *reinterpret_cast<const bf16x8*>(
            &Klds[cur][row * 64 + (((ck * 64 + g4 * 16) ^ h8) >> 1)]);
    }
    f32x4 s[4];
    __builtin_amdgcn_s_setprio(1);
#pragma unroll
    for (int kn = 0; kn < 4; ++kn) {
      f32x4 z = {0.f, 0.f, 0.f, 0.f};
      z = __builtin_amdgcn_mfma_f32_16x16x32_bf16(kf[kn][0], q0, z, 0, 0, 0);
      z = __builtin_amdgcn_mfma_f32_16x16x32_bf16(kf[kn][1], q1, z, 0, 0, 0);
      s[kn] = z;
    }
    __builtin_amdgcn_s_setprio(0);
    if (diag) {
      const int qrel = wid * 16 + l16;
#pragma unroll
      for (int kn = 0; kn < 4; ++kn)
#pragma unroll
        for (int j = 0; j < 4; ++j)
          if (kn * 16 + g4 * 4 + j > qrel) s[kn][j] = -3e38f;
    }
#pragma unroll
    for (int kn = 0; kn < 4; ++kn)
#pragma unroll
      for (int j = 0; j < 4; ++j) s[kn][j] = exp2f(s[kn][j]);
    u16* pl = &Plds[wid][0];
#pragma unroll
    for (int kn = 0; kn < 4; ++kn) {
      bf16x4 w4;
      w4[0] = (__bf16)s[kn][0];
      w4[1] = (__bf16)s[kn][1];
      w4[2] = (__bf16)s[kn][2];
      w4[3] = (__bf16)s[kn][3];
      const int boff = (kn * 32 + g4 * 8) ^ h8;
      *reinterpret_cast<bf16x4*>(&pl[l16 * 64 + (boff >> 1)]) = w4;
    }
    const bf16x8 pa0 = *reinterpret_cast<const bf16x8*>(&pl[l16 * 64 + (((g4 * 16) ^ h8) >> 1)]);
    const bf16x8 pa1 =
        *reinterpret_cast<const bf16x8*>(&pl[l16 * 64 + (((64 + g4 * 16) ^ h8) >> 1)]);
    // V fragments + PV
    bf16x8 vf[4][2];
#pragma unroll
    for (int n = 0; n < 4; ++n) {
      const int row = n * 16 + l16;
#pragma unroll
      for (int ck = 0; ck < 2; ++ck)
        vf[n][ck] = *reinterpret_cast<const bf16x8*>(
            &Vlds[cur][row * 64 + (((ck * 64 + g4 * 16) ^ h8) >> 1)]);
    }
    __builtin_amdgcn_s_setprio(1);
    lacc = __builtin_amdgcn_mfma_f32_16x16x32_bf16(pa0, ones, lacc, 0, 0, 0);
    lacc = __builtin_amdgcn_mfma_f32_16x16x32_bf16(pa1, ones, lacc, 0, 0, 0);
#pragma unroll
    for (int n = 0; n < 4; ++n) {
      acc[n] = __builtin_amdgcn_mfma_f32_16x16x32_bf16(pa0, vf[n][0], acc[n], 0, 0, 0);
      acc[n] = __builtin_amdgcn_mfma_f32_16x16x32_bf16(pa1, vf[n][1], acc[n], 0, 0, 0);
    }
    __builtin_amdgcn_s_setprio(0);
  };

  stage_issue(0, 0);
  __syncthreads();

  for (int kt = 0; kt < it; ++kt) {
    const int cur = kt & 1;
    stage_issue(cur ^ 1, kt + 1);
    tile_step(cur, false);
    __syncthreads();
  }
  tile_step(it & 1, true);  // diagonal tile

  // epilogue: l for row g4*4+j is lacc[j] (all lanes hold it)
  const long obase = (long)(bh >> 4) * 2048 * 1024 + (bh & 15) * 64;
  u16* op = o + obase + ((long)it * 64 + wid * 16 + g4 * 4) * 1024;
#pragma unroll
  for (int n = 0; n < 4; ++n)
#pragma unroll
    for (int j = 0; j < 4; ++j)
      op[j * 1024 + n * 16 + l16] = f2bf(acc[n][j] / lacc[j]);
}

extern "C" void kernel_launch(void* const* d_in, const int* in_sizes, int n_in,
                              void* d_out, int out_size, void* d_ws, size_t ws_size,
                              hipStream_t stream) {
  const float* x = (const float*)d_in[0];
  // d_in[1] = mask (causal tril -- not needed)
  const float* w_qkv = (const float*)d_in[2];
  const float* w_fc = (const float*)d_in[3];
  const float* qw = (const float*)d_in[4];
  const float* kw = (const float*)d_in[5];
  // d_in[6] = subset_attention_size: with a causal mask the split is an identity.
  float* out = (float*)d_out;

  char* ws = (char*)d_ws;
  u16* xb    = (u16*)(ws);                   // 8 MB (reused as vt after gemm_qkv)
  u16* wqkvb = (u16*)(ws + (8L << 20));      // 6 MB
  u16* wfcb  = (u16*)(ws + (14L << 20));     // 2 MB
  u16* qkv   = (u16*)(ws + (16L << 20));     // 24 MB
  u16* ob    = (u16*)(ws + (40L << 20));     // 8 MB
  u16* vt    = xb;                           // xb is dead after gemm_qkv

  cvt_all<<<8192, 256, 0, stream>>>(x, w_qkv, w_fc, xb, wqkvb, wfcb);
  gemm_qkv<<<dim3(32, 24), 256, 0, stream>>>(xb, wqkvb, qkv, qw, kw);
  vtrans<<<1024, 256, 0, stream>>>(qkv, vt);
  attn_causal<<<1024, 256, 0, stream>>>(qkv, vt, ob);
  gemm_fc<<<dim3(32, 16), 256, 0, stream>>>(ob, wfcb, out);
}